// Round 5
// baseline (12388.331 us; speedup 1.0000x reference)
//
#include <hip/hip_runtime.h>

#define B_  2
#define S_  2048
#define D_  2048
#define H_  16
#define HD_ 128

__device__ __forceinline__ ushort f2bf(float f) {
  union { float f; unsigned u; } v; v.f = f;
  unsigned r = v.u + 0x7FFFu + ((v.u >> 16) & 1u);   // RNE
  return (ushort)(r >> 16);
}
__device__ __forceinline__ float bf2f(ushort b) {
  union { unsigned u; float f; } v; v.u = ((unsigned)b) << 16;
  return v.f;
}
// adaptive A-load: abf!=0 -> packed bf16, else fp32
__device__ __forceinline__ float ldA(const void* p, size_t idx, int abf) {
  return abf ? bf2f(((const ushort*)p)[idx]) : ((const float*)p)[idx];
}

// ---------------- tiled GEMM (vector ALU, fp32 accum) ----------------
// C[m,n] = sum_k A[m,k] * B[n,k]   (A MxK, abf selects dtype; B NxK fp32)
// 64x64 tile, 256 threads, 4x4 outputs/thread, K-step 16.
// mode 0: fp32 row-major MxN          -> (float*)Cp
// mode 1: fp32 scatter to (B,H,S,HD)  -> (float*)Cp
// mode 2: bf16 scatter to (B,H,S,HD)  -> (ushort*)Cp
__global__ void sgemm(const void* __restrict__ A, int abf,
                      const float* __restrict__ Bp, void* __restrict__ Cp,
                      int M, int N, int K, int mode)
{
  __shared__ float As[16][65];   // [k][m]
  __shared__ float Bs[16][65];   // [k][n]
  const int tx = threadIdx.x & 15, ty = threadIdx.x >> 4;
  const int bm = blockIdx.x * 64, bn = blockIdx.y * 64;

  float acc[4][4];
#pragma unroll
  for (int i = 0; i < 4; ++i)
#pragma unroll
    for (int j = 0; j < 4; ++j) acc[i][j] = 0.f;

  const int lk = threadIdx.x & 15;          // k_local
  const int lm = (threadIdx.x >> 4) * 4;    // m_local base

  for (int k0 = 0; k0 < K; k0 += 16) {
    __syncthreads();                        // prev compute done
#pragma unroll
    for (int i = 0; i < 4; ++i) {
      As[lk][lm + i] = ldA(A, (size_t)(bm + lm + i) * K + k0 + lk, abf);
      Bs[lk][lm + i] = Bp[(size_t)(bn + lm + i) * K + k0 + lk];
    }
    __syncthreads();                        // tile staged
#pragma unroll
    for (int kk = 0; kk < 16; ++kk) {
      float a[4], bb[4];
#pragma unroll
      for (int i = 0; i < 4; ++i) a[i]  = As[kk][ty * 4 + i];
#pragma unroll
      for (int j = 0; j < 4; ++j) bb[j] = Bs[kk][tx * 4 + j];
#pragma unroll
      for (int i = 0; i < 4; ++i)
#pragma unroll
        for (int j = 0; j < 4; ++j) acc[i][j] += a[i] * bb[j];
    }
  }

#pragma unroll
  for (int i = 0; i < 4; ++i) {
    int m = bm + ty * 4 + i;
    int b = m >> 11, s = m & 2047;          // m = b*S + s
#pragma unroll
    for (int j = 0; j < 4; ++j) {
      int n = bn + tx * 4 + j;
      if (mode == 0) {
        ((float*)Cp)[(size_t)m * N + n] = acc[i][j];
      } else {
        int h = n >> 7, d = n & 127;
        size_t idx = (((size_t)b * H_ + h) * S_ + s) * HD_ + d;
        if (mode == 1) ((float*)Cp)[idx] = acc[i][j];
        else           ((ushort*)Cp)[idx] = f2bf(acc[i][j]);
      }
    }
  }
}

// ---------------- RoPE on Q,K fp32 in (B,H,S,HD), in place ----------------
__global__ void rope_qk(float* __restrict__ Q, float* __restrict__ Kt,
                        const float* __restrict__ cs, const float* __restrict__ sn)
{
  int t = blockIdx.x * 256 + threadIdx.x;   // 2 * B*H*S * 64 threads
  int d  = t & 63;
  int rr = t >> 6;                          // 0 .. 2*B*H*S-1
  int isk = rr >> 16;                       // B*H*S = 65536
  int bhs = rr & 65535;
  int s = bhs & 2047;
  int b = bhs >> 15;
  float* P = isk ? Kt : Q;
  size_t ro = (size_t)bhs * HD_;
  float q0 = P[ro + d], q1 = P[ro + d + 64];
  size_t ci = ((size_t)b * S_ + s) * HD_ + d;
  float c0 = cs[ci], s0 = sn[ci], c1 = cs[ci + 64], s1 = sn[ci + 64];
  P[ro + d]      = q0 * c0 - q1 * s0;
  P[ro + d + 64] = q1 * c1 + q0 * s1;
}

// ---------------- naive attention: one block per query row ----------------
// Q,K fp32 (B,H,S,HD); V bf16 (B,H,S,HD); O bf16 to (B,S,D).
__global__ void attn_naive(const float* __restrict__ Q, const float* __restrict__ Kb,
                           const ushort* __restrict__ Vb, const float* __restrict__ mask,
                           ushort* __restrict__ O)
{
  __shared__ float p[S_];      // scores -> exp
  __shared__ float qs[HD_];
  __shared__ float red[256];

  const int t = threadIdx.x;
  const int qrow = blockIdx.x;            // (b*H + h)*S + s
  const int bh = qrow >> 11;              // /S
  const int b  = bh >> 4;
  const int h  = bh & 15;
  const int s  = qrow & 2047;
  const size_t kbase = (size_t)bh * S_ * HD_;
  const float scale = 0.08838834764831845f;   // 1/sqrt(128)

  if (t < HD_) qs[t] = Q[(size_t)qrow * HD_ + t];
  __syncthreads();

  float lmax = -1e30f;
  for (int key = t; key < S_; key += 256) {
    const float* kr = Kb + kbase + (size_t)key * HD_;
    float acc = 0.f;
#pragma unroll 8
    for (int d = 0; d < HD_; ++d) acc += qs[d] * kr[d];
    float sc = acc * scale + mask[(size_t)b * S_ + key];
    p[key] = sc;
    lmax = fmaxf(lmax, sc);
  }
  red[t] = lmax; __syncthreads();
  for (int o = 128; o > 0; o >>= 1) {
    if (t < o) red[t] = fmaxf(red[t], red[t + o]);
    __syncthreads();
  }
  const float m = red[0];
  __syncthreads();

  float lsum = 0.f;
  for (int key = t; key < S_; key += 256) {
    float e = __expf(p[key] - m);
    p[key] = e;
    lsum += e;
  }
  red[t] = lsum; __syncthreads();
  for (int o = 128; o > 0; o >>= 1) {
    if (t < o) red[t] += red[t + o];
    __syncthreads();
  }
  const float inv = 1.f / red[0];
  __syncthreads();

  if (t < HD_) {
    float acc = 0.f;
    for (int key = 0; key < S_; ++key)
      acc += p[key] * bf2f(Vb[kbase + (size_t)key * HD_ + t]);
    O[((size_t)b * S_ + s) * D_ + h * HD_ + t] = f2bf(acc * inv);
  }
}

// ---------------- launcher ----------------
extern "C" void kernel_launch(void* const* d_in, const int* in_sizes, int n_in,
                              void* d_out, int out_size, void* d_ws, size_t ws_size,
                              hipStream_t stream)
{
  // Guard: silent return -> absmax 0.1357 signature (vs ~0.19 for math bug)
  if (n_in != 8) return;
  if (in_sizes[0] != 8388608) return;       // x  (B,S,D)
  if (in_sizes[1] != 524288)  return;       // cos (B,S,HD)
  if (in_sizes[2] != 524288)  return;       // sin
  if (in_sizes[3] != 4096)    return;       // mask (B,S)
  if (in_sizes[4] != 4194304) return;       // wq (D,D)
  if (in_sizes[7] != 4194304) return;       // wo
  if (out_size != 8388608) return;
  if (ws_size < (size_t)96 * 1024 * 1024) return;

  const float* x    = (const float*)d_in[0];
  const float* cosb = (const float*)d_in[1];
  const float* sinb = (const float*)d_in[2];
  const float* mask = (const float*)d_in[3];
  const float* wq   = (const float*)d_in[4];
  const float* wk   = (const float*)d_in[5];
  const float* wv   = (const float*)d_in[6];
  const float* wo   = (const float*)d_in[7];

  char* ws = (char*)d_ws;
  // layout: Qf fp32 0..32M | Kf fp32 32..64M | Vb bf16 64..80M | AOb bf16 80..96M
  float*  Qf  = (float*)(ws);
  float*  Kf  = (float*)(ws + 33554432);
  ushort* Vb  = (ushort*)(ws + 67108864);
  ushort* AOb = (ushort*)(ws + 83886080);

  dim3 gg(64, 32);   // (M/64, N/64) = (4096/64, 2048/64)
  sgemm<<<gg, 256, 0, stream>>>(x, 0, wq, Qf, 4096, 2048, 2048, 1);
  sgemm<<<gg, 256, 0, stream>>>(x, 0, wk, Kf, 4096, 2048, 2048, 1);
  sgemm<<<gg, 256, 0, stream>>>(x, 0, wv, Vb, 4096, 2048, 2048, 2);

  rope_qk<<<32768, 256, 0, stream>>>(Qf, Kf, cosb, sinb);

  attn_naive<<<65536, 256, 0, stream>>>(Qf, Kf, Vb, mask, AOb);

  // final projection: A = AOb bf16 (B*S x D), B = wo fp32 -> d_out fp32
  sgemm<<<gg, 256, 0, stream>>>(AOb, 1, wo, d_out, 4096, 2048, 2048, 0);
}

// Round 6
// 3158.955 us; speedup vs baseline: 3.9217x; 3.9217x over previous
//
#include <hip/hip_runtime.h>

#define B_  2
#define S_  2048
#define D_  2048
#define H_  16
#define HD_ 128

typedef float  f32x4  __attribute__((ext_vector_type(4)));
typedef __bf16 bf16x8 __attribute__((ext_vector_type(8)));

__device__ __forceinline__ ushort f2bf(float f) {
  union { float f; unsigned u; } v; v.f = f;
  unsigned r = v.u + 0x7FFFu + ((v.u >> 16) & 1u);   // RNE
  return (ushort)(r >> 16);
}
__device__ __forceinline__ float bf2f(ushort b) {
  union { unsigned u; float f; } v; v.u = ((unsigned)b) << 16;
  return v.f;
}
__device__ __forceinline__ __bf16 tobf(float f) {
  union { ushort s; __bf16 b; } c; c.s = f2bf(f); return c.b;
}
__device__ __forceinline__ f32x4 fzero() {
  f32x4 v; v[0] = 0.f; v[1] = 0.f; v[2] = 0.f; v[3] = 0.f; return v;
}
// adaptive A-load: abf!=0 -> packed bf16, else fp32
__device__ __forceinline__ float ldA(const void* p, size_t idx, int abf) {
  return abf ? bf2f(((const ushort*)p)[idx]) : ((const float*)p)[idx];
}

// ---------------- tiled GEMM (vector ALU, fp32 accum) ----------------
// C[m,n] = sum_k A[m,k] * B[n,k]   (A MxK, abf selects dtype; B NxK fp32)
// mode 0: fp32 row-major MxN          -> (float*)Cp
// mode 1: fp32 scatter to (B,H,S,HD)  -> (float*)Cp
// mode 2: bf16 scatter to (B,H,S,HD)  -> (ushort*)Cp
// mode 3: bf16 scatter to (B,H,HD,S)  -> (ushort*)Cp   (transposed V)
__global__ void sgemm(const void* __restrict__ A, int abf,
                      const float* __restrict__ Bp, void* __restrict__ Cp,
                      int M, int N, int K, int mode)
{
  __shared__ float As[16][65];   // [k][m]
  __shared__ float Bs[16][65];   // [k][n]
  const int tx = threadIdx.x & 15, ty = threadIdx.x >> 4;
  const int bm = blockIdx.x * 64, bn = blockIdx.y * 64;

  float acc[4][4];
#pragma unroll
  for (int i = 0; i < 4; ++i)
#pragma unroll
    for (int j = 0; j < 4; ++j) acc[i][j] = 0.f;

  const int lk = threadIdx.x & 15;          // k_local
  const int lm = (threadIdx.x >> 4) * 4;    // m_local base

  for (int k0 = 0; k0 < K; k0 += 16) {
    __syncthreads();                        // prev compute done
#pragma unroll
    for (int i = 0; i < 4; ++i) {
      As[lk][lm + i] = ldA(A, (size_t)(bm + lm + i) * K + k0 + lk, abf);
      Bs[lk][lm + i] = Bp[(size_t)(bn + lm + i) * K + k0 + lk];
    }
    __syncthreads();                        // tile staged
#pragma unroll
    for (int kk = 0; kk < 16; ++kk) {
      float a[4], bb[4];
#pragma unroll
      for (int i = 0; i < 4; ++i) a[i]  = As[kk][ty * 4 + i];
#pragma unroll
      for (int j = 0; j < 4; ++j) bb[j] = Bs[kk][tx * 4 + j];
#pragma unroll
      for (int i = 0; i < 4; ++i)
#pragma unroll
        for (int j = 0; j < 4; ++j) acc[i][j] += a[i] * bb[j];
    }
  }

#pragma unroll
  for (int i = 0; i < 4; ++i) {
    int m = bm + ty * 4 + i;
    int b = m >> 11, s = m & 2047;          // m = b*S + s
#pragma unroll
    for (int j = 0; j < 4; ++j) {
      int n = bn + tx * 4 + j;
      if (mode == 0) {
        ((float*)Cp)[(size_t)m * N + n] = acc[i][j];
      } else {
        int h = n >> 7, d = n & 127;
        if (mode == 1)
          ((float*)Cp)[(((size_t)b * H_ + h) * S_ + s) * HD_ + d] = acc[i][j];
        else if (mode == 2)
          ((ushort*)Cp)[(((size_t)b * H_ + h) * S_ + s) * HD_ + d] = f2bf(acc[i][j]);
        else
          ((ushort*)Cp)[(((size_t)b * H_ + h) * HD_ + d) * S_ + s] = f2bf(acc[i][j]);
      }
    }
  }
}

// ---------------- RoPE on Q,K fp32 in (B,H,S,HD), in place ----------------
__global__ void rope_qk(float* __restrict__ Q, float* __restrict__ Kt,
                        const float* __restrict__ cs, const float* __restrict__ sn)
{
  int t = blockIdx.x * 256 + threadIdx.x;   // 2 * B*H*S * 64 threads
  int d  = t & 63;
  int rr = t >> 6;                          // 0 .. 2*B*H*S-1
  int isk = rr >> 16;                       // B*H*S = 65536
  int bhs = rr & 65535;
  int s = bhs & 2047;
  int b = bhs >> 15;
  float* P = isk ? Kt : Q;
  size_t ro = (size_t)bhs * HD_;
  float q0 = P[ro + d], q1 = P[ro + d + 64];
  size_t ci = ((size_t)b * S_ + s) * HD_ + d;
  float c0 = cs[ci], s0 = sn[ci], c1 = cs[ci + 64], s1 = sn[ci + 64];
  P[ro + d]      = q0 * c0 - q1 * s0;
  P[ro + d + 64] = q1 * c1 + q0 * s1;
}

// ---------------- flash attention (MFMA) ----------------
// grid (S/64, B*H), 256 thr = 4 waves x 16 q-rows. KV tiles of 64.
// Q,K fp32 (B,H,S,HD) -> bf16 at MFMA input. VT bf16 (B,H,HD,S).
// Padded LDS, register-staged (structure = R2, verified mappings).
#define KP 136   // 128+8 ushorts, keeps 16B-aligned b128 reads
#define VP 72    // 64+8
__global__ __launch_bounds__(256, 2)
void flash(const float* __restrict__ Q, const float* __restrict__ Kk,
           const ushort* __restrict__ VT, const float* __restrict__ mask,
           ushort* __restrict__ O)
{
  __shared__ __align__(16) ushort kt_s[64 * KP];
  __shared__ __align__(16) ushort vt_s[128 * VP];
  __shared__ __align__(16) ushort pt[4][16 * VP];

  const int tid = threadIdx.x;
  const int wave = tid >> 6, lane = tid & 63;
  const int qt = lane >> 4, ln = lane & 15;
  const int bh = blockIdx.y, b = bh >> 4, h = bh & 15;
  const size_t base  = (size_t)bh * S_ * HD_;   // Q,K fp32
  const size_t baseT = (size_t)bh * HD_ * S_;   // VT bf16
  const int q0 = blockIdx.x * 64 + wave * 16;

  // Q fragment: A-layout row=ln, k = kk*32 + qt*8 + j  (fp32 -> bf16)
  bf16x8 qf[4];
  {
    const float* qrow = Q + base + (size_t)(q0 + ln) * HD_;
#pragma unroll
    for (int kk = 0; kk < 4; ++kk)
#pragma unroll
      for (int j = 0; j < 8; ++j) qf[kk][j] = tobf(qrow[kk * 32 + qt * 8 + j]);
  }

  f32x4 accO[8];
#pragma unroll
  for (int i = 0; i < 8; ++i) accO[i] = fzero();
  float mrun[4] = {-1e30f, -1e30f, -1e30f, -1e30f};
  float lrun[4] = {0.f, 0.f, 0.f, 0.f};
  const float scale = 0.08838834764831845f;  // 1/sqrt(128)

  // staging: K fp32 tile 64x128 -> 8 float4/thread; VT bf16 -> 4 chunks/thread
  const int krow = tid >> 2, kcg = tid & 3;   // K row, col-group (32 floats)
  const int vrw  = tid >> 3, vch = tid & 7;   // VT rows it*32+vrw, chunk vch

  float4 rK[8];
  bf16x8 rV[4];
  auto loadKV = [&](int k0) {
    const float* kr = Kk + base + (size_t)(k0 + krow) * HD_ + kcg * 32;
#pragma unroll
    for (int j = 0; j < 8; ++j) rK[j] = ((const float4*)kr)[j];
#pragma unroll
    for (int it = 0; it < 4; ++it)
      rV[it] = *(const bf16x8*)(VT + baseT + (size_t)(it * 32 + vrw) * S_ + k0 + vch * 8);
  };
  loadKV(0);

  for (int k0 = 0; k0 < S_; k0 += 64) {
    __syncthreads();                         // all waves done with prev tile
#pragma unroll
    for (int j = 0; j < 8; ++j)
      *(ushort4*)&kt_s[krow * KP + kcg * 32 + j * 4] =
          make_ushort4(f2bf(rK[j].x), f2bf(rK[j].y), f2bf(rK[j].z), f2bf(rK[j].w));
#pragma unroll
    for (int it = 0; it < 4; ++it)
      *(bf16x8*)&vt_s[(it * 32 + vrw) * VP + vch * 8] = rV[it];
    __syncthreads();                         // staged tile visible
    if (k0 + 64 < S_) loadKV(k0 + 64);       // prefetch next (overlaps MFMA)

    // QK^T: S[q][k] 16x64 per wave
    f32x4 sc[4];
#pragma unroll
    for (int nf = 0; nf < 4; ++nf) {
      f32x4 a = fzero();
      int row = nf * 16 + ln;
#pragma unroll
      for (int kk = 0; kk < 4; ++kk) {
        bf16x8 kf = *(const bf16x8*)&kt_s[row * KP + (kk * 4 + qt) * 8];
        a = __builtin_amdgcn_mfma_f32_16x16x32_bf16(qf[kk], kf, a, 0, 0, 0);
      }
      sc[nf] = a;
    }

    // scale + mask, online softmax (rows owned: r = qt*4+i)
    float sv[4][4];
#pragma unroll
    for (int nf = 0; nf < 4; ++nf) {
      float mk = mask[(size_t)b * S_ + k0 + nf * 16 + ln];
#pragma unroll
      for (int i = 0; i < 4; ++i) sv[nf][i] = sc[nf][i] * scale + mk;
    }
    float fsc[4];
#pragma unroll
    for (int i = 0; i < 4; ++i) {
      float m = fmaxf(fmaxf(sv[0][i], sv[1][i]), fmaxf(sv[2][i], sv[3][i]));
#pragma unroll
      for (int o = 1; o < 16; o <<= 1) m = fmaxf(m, __shfl_xor(m, o));
      float mn = fmaxf(mrun[i], m);
      fsc[i] = __expf(mrun[i] - mn);
      mrun[i] = mn;
    }
#pragma unroll
    for (int i = 0; i < 4; ++i) {
      float t = 0.f;
      int r = qt * 4 + i;
#pragma unroll
      for (int nf = 0; nf < 4; ++nf) {
        float p = __expf(sv[nf][i] - mrun[i]);
        ushort pq = f2bf(p);
        pt[wave][r * VP + nf * 16 + ln] = pq;
        t += bf2f(pq);                      // sum the QUANTIZED P -> exact norm
      }
#pragma unroll
      for (int o = 1; o < 16; o <<= 1) t += __shfl_xor(t, o);
      lrun[i] = lrun[i] * fsc[i] + t;
    }
#pragma unroll
    for (int nfo = 0; nfo < 8; ++nfo)
#pragma unroll
      for (int i = 0; i < 4; ++i) accO[nfo][i] *= fsc[i];

    __syncthreads();                        // conservative: P visible

    // PV: accO[16 q][128 d] += P[16][64] * V[64][128]
#pragma unroll
    for (int kk2 = 0; kk2 < 2; ++kk2) {
      bf16x8 pf = *(const bf16x8*)&pt[wave][ln * VP + (kk2 * 4 + qt) * 8];
#pragma unroll
      for (int nfo = 0; nfo < 8; ++nfo) {
        int vrow = nfo * 16 + ln;
        bf16x8 vf = *(const bf16x8*)&vt_s[vrow * VP + (kk2 * 4 + qt) * 8];
        accO[nfo] = __builtin_amdgcn_mfma_f32_16x16x32_bf16(pf, vf, accO[nfo], 0, 0, 0);
      }
    }
  }

  // epilogue: O (B,S,D) bf16
  float inv[4];
#pragma unroll
  for (int i = 0; i < 4; ++i) inv[i] = 1.f / lrun[i];
#pragma unroll
  for (int nfo = 0; nfo < 8; ++nfo)
#pragma unroll
    for (int i = 0; i < 4; ++i) {
      size_t idx = ((size_t)b * S_ + q0 + qt * 4 + i) * D_ + h * HD_ + nfo * 16 + ln;
      O[idx] = f2bf(accO[nfo][i] * inv[i]);
    }
}

// ---------------- launcher ----------------
extern "C" void kernel_launch(void* const* d_in, const int* in_sizes, int n_in,
                              void* d_out, int out_size, void* d_ws, size_t ws_size,
                              hipStream_t stream)
{
  if (n_in != 8) return;
  if (in_sizes[0] != 8388608) return;       // x  (B,S,D)
  if (in_sizes[3] != 4096)    return;       // mask (B,S)
  if (out_size != 8388608) return;
  if (ws_size < (size_t)96 * 1024 * 1024) return;

  const float* x    = (const float*)d_in[0];
  const float* cosb = (const float*)d_in[1];
  const float* sinb = (const float*)d_in[2];
  const float* mask = (const float*)d_in[3];
  const float* wq   = (const float*)d_in[4];
  const float* wk   = (const float*)d_in[5];
  const float* wv   = (const float*)d_in[6];
  const float* wo   = (const float*)d_in[7];

  char* ws = (char*)d_ws;
  // layout: Qf fp32 0..32M | Kf fp32 32..64M | VTb bf16 64..80M | AOb bf16 80..96M
  float*  Qf  = (float*)(ws);
  float*  Kf  = (float*)(ws + 33554432);
  ushort* VTb = (ushort*)(ws + 67108864);
  ushort* AOb = (ushort*)(ws + 83886080);

  dim3 gg(64, 32);   // (M/64, N/64) = (4096/64, 2048/64)
  sgemm<<<gg, 256, 0, stream>>>(x, 0, wq, Qf,  4096, 2048, 2048, 1);
  sgemm<<<gg, 256, 0, stream>>>(x, 0, wk, Kf,  4096, 2048, 2048, 1);
  sgemm<<<gg, 256, 0, stream>>>(x, 0, wv, VTb, 4096, 2048, 2048, 3);

  rope_qk<<<32768, 256, 0, stream>>>(Qf, Kf, cosb, sinb);

  flash<<<dim3(32, 32), 256, 0, stream>>>(Qf, Kf, VTb, mask, AOb);

  // final projection: A = AOb bf16 (B*S x D), B = wo fp32 -> d_out fp32
  sgemm<<<gg, 256, 0, stream>>>(AOb, 1, wo, d_out, 4096, 2048, 2048, 0);
}

// Round 7
// 766.700 us; speedup vs baseline: 16.1580x; 4.1202x over previous
//
#include <hip/hip_runtime.h>

#define B_  2
#define S_  2048
#define D_  2048
#define H_  16
#define HD_ 128

typedef float  f32x4  __attribute__((ext_vector_type(4)));
typedef __bf16 bf16x8 __attribute__((ext_vector_type(8)));

__device__ __forceinline__ ushort f2bf(float f) {
  union { float f; unsigned u; } v; v.f = f;
  unsigned r = v.u + 0x7FFFu + ((v.u >> 16) & 1u);   // RNE
  return (ushort)(r >> 16);
}
__device__ __forceinline__ float bf2f(ushort b) {
  union { unsigned u; float f; } v; v.u = ((unsigned)b) << 16;
  return v.f;
}
__device__ __forceinline__ __bf16 tobf(float f) {
  union { ushort s; __bf16 b; } c; c.s = f2bf(f); return c.b;
}
__device__ __forceinline__ f32x4 fzero() {
  f32x4 v; v[0] = 0.f; v[1] = 0.f; v[2] = 0.f; v[3] = 0.f; return v;
}

// ---------------- MFMA GEMM: C[m,n] = sum_k A[m,k]*B[n,k] ----------------
// 128x128 tile, BK=32, 4 waves (2x2). Register-staged, padded LDS (verified
// structure: fragment maps shared with flash). ABF: A dtype (1=bf16, 0=fp32).
// B is always fp32, converted to bf16 inline during staging.
// mode 0: fp32 row-major MxN          -> (float*)Cp
// mode 1: fp32 scatter to (B,H,S,HD)  -> (float*)Cp
// mode 3: bf16 scatter to (B,H,HD,S)  -> (ushort*)Cp   (transposed V)
#define LP 40   // padded row stride in ushorts (32 + 8): 80B -> worst 2-way alias
template<int ABF>
__global__ __launch_bounds__(256, 2)
void mgemm(const void* __restrict__ A, const float* __restrict__ Bp,
           void* __restrict__ Cp, int M, int N, int K, int mode)
{
  __shared__ __align__(16) ushort lA[2][128 * LP];
  __shared__ __align__(16) ushort lB[2][128 * LP];
  const int tid  = threadIdx.x;
  const int wave = tid >> 6, lane = tid & 63;
  const int qt = lane >> 4, ln = lane & 15;
  const int wr = wave >> 1, wc = wave & 1;
  const int bm = blockIdx.x * 128, bn = blockIdx.y * 128;

  f32x4 acc[4][4];
#pragma unroll
  for (int a = 0; a < 4; ++a)
#pragma unroll
    for (int b = 0; b < 4; ++b) acc[a][b] = fzero();

  // staging: thread covers rows r0 and r0+64, col chunk c0 (8 elems)
  const int r0 = tid >> 2, c0 = tid & 3;

  bf16x8 rA0, rA1, rB0, rB1;
  auto cvt8 = [](const float* p) {
    bf16x8 o;
#pragma unroll
    for (int j = 0; j < 8; ++j) o[j] = tobf(p[j]);
    return o;
  };
  auto load = [&](int kt) {
    const size_t co = (size_t)kt + c0 * 8;
    if (ABF) {
      rA0 = *(const bf16x8*)((const ushort*)A + (size_t)(bm + r0)      * K + co);
      rA1 = *(const bf16x8*)((const ushort*)A + (size_t)(bm + r0 + 64) * K + co);
    } else {
      rA0 = cvt8((const float*)A + (size_t)(bm + r0)      * K + co);
      rA1 = cvt8((const float*)A + (size_t)(bm + r0 + 64) * K + co);
    }
    rB0 = cvt8(Bp + (size_t)(bn + r0)      * K + co);
    rB1 = cvt8(Bp + (size_t)(bn + r0 + 64) * K + co);
  };
  load(0);

  const int nk = K >> 5;
  int cur = 0;
  for (int kt = 0; kt < nk; ++kt) {
    *(bf16x8*)&lA[cur][r0 * LP + c0 * 8]        = rA0;
    *(bf16x8*)&lA[cur][(r0 + 64) * LP + c0 * 8] = rA1;
    *(bf16x8*)&lB[cur][r0 * LP + c0 * 8]        = rB0;
    *(bf16x8*)&lB[cur][(r0 + 64) * LP + c0 * 8] = rB1;
    __syncthreads();                       // writes visible; prev reads done
    if (kt + 1 < nk) load((kt + 1) << 5);  // prefetch overlaps MFMA below

    bf16x8 af[4], bfr[4];
#pragma unroll
    for (int mf = 0; mf < 4; ++mf)
      af[mf] = *(const bf16x8*)&lA[cur][(wr * 64 + mf * 16 + ln) * LP + qt * 8];
#pragma unroll
    for (int nf = 0; nf < 4; ++nf)
      bfr[nf] = *(const bf16x8*)&lB[cur][(wc * 64 + nf * 16 + ln) * LP + qt * 8];
#pragma unroll
    for (int mf = 0; mf < 4; ++mf)
#pragma unroll
      for (int nf = 0; nf < 4; ++nf)
        acc[mf][nf] = __builtin_amdgcn_mfma_f32_16x16x32_bf16(
            af[mf], bfr[nf], acc[mf][nf], 0, 0, 0);
    cur ^= 1;
  }

  // epilogue: C/D layout col=lane&15, row=(lane>>4)*4+reg  [HW-verified]
#pragma unroll
  for (int mf = 0; mf < 4; ++mf)
#pragma unroll
    for (int nf = 0; nf < 4; ++nf) {
      int m0 = bm + wr * 64 + mf * 16 + qt * 4;
      int n  = bn + wc * 64 + nf * 16 + ln;
#pragma unroll
      for (int i = 0; i < 4; ++i) {
        int m = m0 + i;
        if (mode == 0) {
          ((float*)Cp)[(size_t)m * N + n] = acc[mf][nf][i];
        } else {
          int b = m >> 11, s = m & 2047;     // m = b*S + s
          int h = n >> 7,  d = n & 127;      // n = h*HD + d
          if (mode == 1)
            ((float*)Cp)[(((size_t)b * H_ + h) * S_ + s) * HD_ + d] = acc[mf][nf][i];
          else
            ((ushort*)Cp)[(((size_t)b * H_ + h) * HD_ + d) * S_ + s] = f2bf(acc[mf][nf][i]);
        }
      }
    }
}

// ---------------- RoPE on Q,K fp32 in (B,H,S,HD), in place ----------------
__global__ void rope_qk(float* __restrict__ Q, float* __restrict__ Kt,
                        const float* __restrict__ cs, const float* __restrict__ sn)
{
  int t = blockIdx.x * 256 + threadIdx.x;   // 2 * B*H*S * 64 threads
  int d  = t & 63;
  int rr = t >> 6;                          // 0 .. 2*B*H*S-1
  int isk = rr >> 16;                       // B*H*S = 65536
  int bhs = rr & 65535;
  int s = bhs & 2047;
  int b = bhs >> 15;
  float* P = isk ? Kt : Q;
  size_t ro = (size_t)bhs * HD_;
  float q0 = P[ro + d], q1 = P[ro + d + 64];
  size_t ci = ((size_t)b * S_ + s) * HD_ + d;
  float c0 = cs[ci], s0 = sn[ci], c1 = cs[ci + 64], s1 = sn[ci + 64];
  P[ro + d]      = q0 * c0 - q1 * s0;
  P[ro + d + 64] = q1 * c1 + q0 * s1;
}

// ---------------- flash attention (MFMA) — verified R6 ----------------
#define KP 136   // 128+8 ushorts
#define VP 72    // 64+8
__global__ __launch_bounds__(256, 2)
void flash(const float* __restrict__ Q, const float* __restrict__ Kk,
           const ushort* __restrict__ VT, const float* __restrict__ mask,
           ushort* __restrict__ O)
{
  __shared__ __align__(16) ushort kt_s[64 * KP];
  __shared__ __align__(16) ushort vt_s[128 * VP];
  __shared__ __align__(16) ushort pt[4][16 * VP];

  const int tid = threadIdx.x;
  const int wave = tid >> 6, lane = tid & 63;
  const int qt = lane >> 4, ln = lane & 15;
  const int bh = blockIdx.y, b = bh >> 4, h = bh & 15;
  const size_t base  = (size_t)bh * S_ * HD_;   // Q,K fp32
  const size_t baseT = (size_t)bh * HD_ * S_;   // VT bf16
  const int q0 = blockIdx.x * 64 + wave * 16;

  bf16x8 qf[4];
  {
    const float* qrow = Q + base + (size_t)(q0 + ln) * HD_;
#pragma unroll
    for (int kk = 0; kk < 4; ++kk)
#pragma unroll
      for (int j = 0; j < 8; ++j) qf[kk][j] = tobf(qrow[kk * 32 + qt * 8 + j]);
  }

  f32x4 accO[8];
#pragma unroll
  for (int i = 0; i < 8; ++i) accO[i] = fzero();
  float mrun[4] = {-1e30f, -1e30f, -1e30f, -1e30f};
  float lrun[4] = {0.f, 0.f, 0.f, 0.f};
  const float scale = 0.08838834764831845f;  // 1/sqrt(128)

  const int krow = tid >> 2, kcg = tid & 3;   // K row, col-group (32 floats)
  const int vrw  = tid >> 3, vch = tid & 7;   // VT rows it*32+vrw, chunk vch

  float4 rK[8];
  bf16x8 rV[4];
  auto loadKV = [&](int k0) {
    const float* kr = Kk + base + (size_t)(k0 + krow) * HD_ + kcg * 32;
#pragma unroll
    for (int j = 0; j < 8; ++j) rK[j] = ((const float4*)kr)[j];
#pragma unroll
    for (int it = 0; it < 4; ++it)
      rV[it] = *(const bf16x8*)(VT + baseT + (size_t)(it * 32 + vrw) * S_ + k0 + vch * 8);
  };
  loadKV(0);

  for (int k0 = 0; k0 < S_; k0 += 64) {
    __syncthreads();
#pragma unroll
    for (int j = 0; j < 8; ++j)
      *(ushort4*)&kt_s[krow * KP + kcg * 32 + j * 4] =
          make_ushort4(f2bf(rK[j].x), f2bf(rK[j].y), f2bf(rK[j].z), f2bf(rK[j].w));
#pragma unroll
    for (int it = 0; it < 4; ++it)
      *(bf16x8*)&vt_s[(it * 32 + vrw) * VP + vch * 8] = rV[it];
    __syncthreads();
    if (k0 + 64 < S_) loadKV(k0 + 64);

    f32x4 sc[4];
#pragma unroll
    for (int nf = 0; nf < 4; ++nf) {
      f32x4 a = fzero();
      int row = nf * 16 + ln;
#pragma unroll
      for (int kk = 0; kk < 4; ++kk) {
        bf16x8 kf = *(const bf16x8*)&kt_s[row * KP + (kk * 4 + qt) * 8];
        a = __builtin_amdgcn_mfma_f32_16x16x32_bf16(qf[kk], kf, a, 0, 0, 0);
      }
      sc[nf] = a;
    }

    float sv[4][4];
#pragma unroll
    for (int nf = 0; nf < 4; ++nf) {
      float mk = mask[(size_t)b * S_ + k0 + nf * 16 + ln];
#pragma unroll
      for (int i = 0; i < 4; ++i) sv[nf][i] = sc[nf][i] * scale + mk;
    }
    float fsc[4];
#pragma unroll
    for (int i = 0; i < 4; ++i) {
      float m = fmaxf(fmaxf(sv[0][i], sv[1][i]), fmaxf(sv[2][i], sv[3][i]));
#pragma unroll
      for (int o = 1; o < 16; o <<= 1) m = fmaxf(m, __shfl_xor(m, o));
      float mn = fmaxf(mrun[i], m);
      fsc[i] = __expf(mrun[i] - mn);
      mrun[i] = mn;
    }
#pragma unroll
    for (int i = 0; i < 4; ++i) {
      float t = 0.f;
      int r = qt * 4 + i;
#pragma unroll
      for (int nf = 0; nf < 4; ++nf) {
        float p = __expf(sv[nf][i] - mrun[i]);
        ushort pq = f2bf(p);
        pt[wave][r * VP + nf * 16 + ln] = pq;
        t += bf2f(pq);                      // sum the QUANTIZED P -> exact norm
      }
#pragma unroll
      for (int o = 1; o < 16; o <<= 1) t += __shfl_xor(t, o);
      lrun[i] = lrun[i] * fsc[i] + t;
    }
#pragma unroll
    for (int nfo = 0; nfo < 8; ++nfo)
#pragma unroll
      for (int i = 0; i < 4; ++i) accO[nfo][i] *= fsc[i];

    __syncthreads();

#pragma unroll
    for (int kk2 = 0; kk2 < 2; ++kk2) {
      bf16x8 pf = *(const bf16x8*)&pt[wave][ln * VP + (kk2 * 4 + qt) * 8];
#pragma unroll
      for (int nfo = 0; nfo < 8; ++nfo) {
        int vrow = nfo * 16 + ln;
        bf16x8 vf = *(const bf16x8*)&vt_s[vrow * VP + (kk2 * 4 + qt) * 8];
        accO[nfo] = __builtin_amdgcn_mfma_f32_16x16x32_bf16(pf, vf, accO[nfo], 0, 0, 0);
      }
    }
  }

  float inv[4];
#pragma unroll
  for (int i = 0; i < 4; ++i) inv[i] = 1.f / lrun[i];
#pragma unroll
  for (int nfo = 0; nfo < 8; ++nfo)
#pragma unroll
    for (int i = 0; i < 4; ++i) {
      size_t idx = ((size_t)b * S_ + q0 + qt * 4 + i) * D_ + h * HD_ + nfo * 16 + ln;
      O[idx] = f2bf(accO[nfo][i] * inv[i]);
    }
}

// ---------------- launcher ----------------
extern "C" void kernel_launch(void* const* d_in, const int* in_sizes, int n_in,
                              void* d_out, int out_size, void* d_ws, size_t ws_size,
                              hipStream_t stream)
{
  if (n_in != 8) return;
  if (in_sizes[0] != 8388608) return;       // x  (B,S,D)
  if (in_sizes[3] != 4096)    return;       // mask (B,S)
  if (out_size != 8388608) return;
  if (ws_size < (size_t)96 * 1024 * 1024) return;

  const float* x    = (const float*)d_in[0];
  const float* cosb = (const float*)d_in[1];
  const float* sinb = (const float*)d_in[2];
  const float* mask = (const float*)d_in[3];
  const float* wq   = (const float*)d_in[4];
  const float* wk   = (const float*)d_in[5];
  const float* wv   = (const float*)d_in[6];
  const float* wo   = (const float*)d_in[7];

  char* ws = (char*)d_ws;
  // layout: Qf fp32 0..32M | Kf fp32 32..64M | VTb bf16 64..80M | AOb bf16 80..96M
  float*  Qf  = (float*)(ws);
  float*  Kf  = (float*)(ws + 33554432);
  ushort* VTb = (ushort*)(ws + 67108864);
  ushort* AOb = (ushort*)(ws + 83886080);

  dim3 gg(32, 16);   // (M/128, N/128) = (4096/128, 2048/128)
  mgemm<0><<<gg, 256, 0, stream>>>(x, wq, Qf,  4096, 2048, 2048, 1);
  mgemm<0><<<gg, 256, 0, stream>>>(x, wk, Kf,  4096, 2048, 2048, 1);
  mgemm<0><<<gg, 256, 0, stream>>>(x, wv, VTb, 4096, 2048, 2048, 3);

  rope_qk<<<32768, 256, 0, stream>>>(Qf, Kf, cosb, sinb);

  flash<<<dim3(32, 32), 256, 0, stream>>>(Qf, Kf, VTb, mask, AOb);

  // final projection: A = AOb bf16 (B*S x D), B = wo fp32 -> d_out fp32
  mgemm<1><<<gg, 256, 0, stream>>>(AOb, wo, d_out, 4096, 2048, 2048, 0);
}

// Round 8
// 389.495 us; speedup vs baseline: 31.8061x; 1.9684x over previous
//
#include <hip/hip_runtime.h>

#define B_  2
#define S_  2048
#define D_  2048
#define H_  16
#define HD_ 128

typedef float  f32x4  __attribute__((ext_vector_type(4)));
typedef __bf16 bf16x8 __attribute__((ext_vector_type(8)));

__device__ __forceinline__ void gl16(const void* g, void* l) {
  __builtin_amdgcn_global_load_lds(
      (const __attribute__((address_space(1))) unsigned int*)g,
      (__attribute__((address_space(3))) unsigned int*)l, 16, 0, 0);
}

__device__ __forceinline__ ushort f2bf(float f) {
  union { float f; unsigned u; } v; v.f = f;
  unsigned r = v.u + 0x7FFFu + ((v.u >> 16) & 1u);   // RNE
  return (ushort)(r >> 16);
}
__device__ __forceinline__ float bf2f(ushort b) {
  union { unsigned u; float f; } v; v.u = ((unsigned)b) << 16;
  return v.f;
}
__device__ __forceinline__ f32x4 fzero() {
  f32x4 v; v[0] = 0.f; v[1] = 0.f; v[2] = 0.f; v[3] = 0.f; return v;
}

// ---------------- fp32 -> bf16 convert (vectorized) ----------------
__global__ void cvt4(const float* __restrict__ s, ushort* __restrict__ d, int n4) {
  int i = blockIdx.x * blockDim.x + threadIdx.x;
  if (i >= n4) return;
  float4 v = ((const float4*)s)[i];
  ushort4 o = make_ushort4(f2bf(v.x), f2bf(v.y), f2bf(v.z), f2bf(v.w));
  ((ushort4*)d)[i] = o;
}

// ---------------- MFMA GEMM (m97 recipe, R1-verified) ----------------
// C[m,n] = sum_k A[m,k]*B[n,k], both bf16 row-major (K fast).
// 128x128 tile, BK=32, 4 waves (2x2), global_load_lds w16, dbuf LDS.
// Chunk swizzle: slot = ch ^ ((row>>1)&3), pre-swizzled global source.
// MODE 0: fp32 row-major MxN -> (float*)
// MODE 1: bf16 scatter (B,H,S,HD) -> (ushort*)
// MODE 3: bf16 scatter (B,H,HD,S) -> (ushort*)   (transposed V)
template<int MODE>
__global__ __launch_bounds__(256, 2)
void gemm_bt(const ushort* __restrict__ A, const ushort* __restrict__ Bp,
             void* __restrict__ Cp, int M, int N, int K)
{
  __shared__ __align__(16) ushort lds[2][2][128 * 32];
  const int tid  = threadIdx.x;
  const int wave = tid >> 6, lane = tid & 63;
  const int qt = lane >> 4, ln = lane & 15;
  const int wr = wave >> 1, wc = wave & 1;
  const int bm = blockIdx.x * 128, bn = blockIdx.y * 128;

  f32x4 acc[4][4];
#pragma unroll
  for (int a = 0; a < 4; ++a)
#pragma unroll
    for (int b = 0; b < 4; ++b) acc[a][b] = fzero();

  auto stage = [&](int buf, int kt) {
#pragma unroll
    for (int it = 0; it < 2; ++it) {
      int c = it * 256 + tid;
      int row = c >> 2, ch = c & 3;
      int chs = ch ^ ((row >> 1) & 3);
      gl16(A  + (size_t)(bm + row) * K + kt + chs * 8,
           (void*)&lds[buf][0][(it * 256 + wave * 64) * 8]);
      gl16(Bp + (size_t)(bn + row) * K + kt + chs * 8,
           (void*)&lds[buf][1][(it * 256 + wave * 64) * 8]);
    }
  };

  const int nk = K >> 5;
  stage(0, 0);
  int cur = 0;
  for (int kt = 0; kt < nk; ++kt) {
    __syncthreads();                      // drains vmcnt -> buf[cur] staged
    if (kt + 1 < nk) stage(cur ^ 1, (kt + 1) << 5);
    bf16x8 af[4], bfr[4];
#pragma unroll
    for (int mf = 0; mf < 4; ++mf) {
      int row = wr * 64 + mf * 16 + ln;
      int sl = qt ^ ((row >> 1) & 3);
      af[mf] = *(const bf16x8*)&lds[cur][0][row * 32 + sl * 8];
    }
#pragma unroll
    for (int nf = 0; nf < 4; ++nf) {
      int row = wc * 64 + nf * 16 + ln;
      int sl = qt ^ ((row >> 1) & 3);
      bfr[nf] = *(const bf16x8*)&lds[cur][1][row * 32 + sl * 8];
    }
#pragma unroll
    for (int mf = 0; mf < 4; ++mf)
#pragma unroll
      for (int nf = 0; nf < 4; ++nf)
        acc[mf][nf] = __builtin_amdgcn_mfma_f32_16x16x32_bf16(
            af[mf], bfr[nf], acc[mf][nf], 0, 0, 0);
    cur ^= 1;
  }

  // epilogue: C/D layout col=lane&15, row=(lane>>4)*4+reg  [HW-verified]
#pragma unroll
  for (int mf = 0; mf < 4; ++mf)
#pragma unroll
    for (int nf = 0; nf < 4; ++nf) {
      int m0 = bm + wr * 64 + mf * 16 + qt * 4;
      int n  = bn + wc * 64 + nf * 16 + ln;
#pragma unroll
      for (int i = 0; i < 4; ++i) {
        int m = m0 + i;
        if (MODE == 0) {
          ((float*)Cp)[(size_t)m * N + n] = acc[mf][nf][i];
        } else {
          int b = m >> 11, s = m & 2047;     // m = b*S + s
          int h = n >> 7,  d = n & 127;      // n = h*HD + d
          if (MODE == 1)
            ((ushort*)Cp)[(((size_t)b * H_ + h) * S_ + s) * HD_ + d] = f2bf(acc[mf][nf][i]);
          else
            ((ushort*)Cp)[(((size_t)b * H_ + h) * HD_ + d) * S_ + s] = f2bf(acc[mf][nf][i]);
        }
      }
    }
}

// ---------------- RoPE on Q,K bf16 in (B,H,S,HD), in place ----------------
__global__ void rope_qk(ushort* __restrict__ Q, ushort* __restrict__ Kt,
                        const float* __restrict__ cs, const float* __restrict__ sn)
{
  int t = blockIdx.x * 256 + threadIdx.x;   // 2 * B*H*S * 64 threads
  int d  = t & 63;
  int rr = t >> 6;                          // 0 .. 2*B*H*S-1
  int isk = rr >> 16;                       // B*H*S = 65536
  int bhs = rr & 65535;
  int s = bhs & 2047;
  int b = bhs >> 15;
  ushort* P = isk ? Kt : Q;
  size_t ro = (size_t)bhs * HD_;
  float q0 = bf2f(P[ro + d]), q1 = bf2f(P[ro + d + 64]);
  size_t ci = ((size_t)b * S_ + s) * HD_ + d;
  float c0 = cs[ci], s0 = sn[ci], c1 = cs[ci + 64], s1 = sn[ci + 64];
  P[ro + d]      = f2bf(q0 * c0 - q1 * s0);
  P[ro + d + 64] = f2bf(q1 * c1 + q0 * s1);
}

// ---------------- flash attention (R1-verified gl_lds structure) ----------
// grid (S/64, B*H), 256 thr = 4 waves x 16 q-rows. KV tiles of 64.
// K tile [64][128]: slot = ch ^ (row&7). VT tile [128][64]: slot = ch ^ (d&7).
// P per-wave [16][64]: slot = ch ^ (r&7). 40KB LDS total.
__global__ __launch_bounds__(256, 2)
void flash(const ushort* __restrict__ Q, const ushort* __restrict__ Kk,
           const ushort* __restrict__ VT, const float* __restrict__ mask,
           ushort* __restrict__ O)
{
  __shared__ __align__(16) ushort kt_s[64 * 128];
  __shared__ __align__(16) ushort vt_s[128 * 64];
  __shared__ __align__(16) ushort pt[4][16 * 64];

  const int tid = threadIdx.x;
  const int wave = tid >> 6, lane = tid & 63;
  const int qt = lane >> 4, ln = lane & 15;
  const int bh = blockIdx.y, b = bh >> 4, h = bh & 15;
  const size_t base  = (size_t)bh * S_ * HD_;
  const size_t baseT = (size_t)bh * HD_ * S_;
  const int q0 = blockIdx.x * 64 + wave * 16;

  bf16x8 qf[4];
  {
    const ushort* qrow = Q + base + (size_t)(q0 + ln) * HD_;
#pragma unroll
    for (int kk = 0; kk < 4; ++kk)
      qf[kk] = *(const bf16x8*)(qrow + kk * 32 + qt * 8);
  }

  f32x4 accO[8];
#pragma unroll
  for (int i = 0; i < 8; ++i) accO[i] = fzero();
  float mrun[4] = {-1e30f, -1e30f, -1e30f, -1e30f};
  float lrun[4] = {0.f, 0.f, 0.f, 0.f};
  const float scale = 0.08838834764831845f;  // 1/sqrt(128)

  for (int k0 = 0; k0 < S_; k0 += 64) {
    __syncthreads();                         // all waves done with prev tiles
#pragma unroll
    for (int it = 0; it < 4; ++it) {         // K tile: 1024 chunks
      int c = it * 256 + tid;
      int row = c >> 4, ch = c & 15;
      int chs = ch ^ (row & 7);
      gl16(Kk + base + (size_t)(k0 + row) * HD_ + chs * 8,
           (void*)&kt_s[(it * 256 + wave * 64) * 8]);
    }
#pragma unroll
    for (int it = 0; it < 4; ++it) {         // VT tile: 1024 chunks
      int c = it * 256 + tid;
      int row = c >> 3, ch = c & 7;
      int chs = ch ^ (row & 7);
      gl16(VT + baseT + (size_t)row * S_ + k0 + chs * 8,
           (void*)&vt_s[(it * 256 + wave * 64) * 8]);
    }
    __syncthreads();                         // drains vmcnt

    // QK^T: S[q][k] 16x64 per wave
    f32x4 sc[4];
#pragma unroll
    for (int nf = 0; nf < 4; ++nf) {
      f32x4 a = fzero();
      int row = nf * 16 + ln;
#pragma unroll
      for (int kk = 0; kk < 4; ++kk) {
        int sl = (kk * 4 + qt) ^ (row & 7);
        bf16x8 kf = *(const bf16x8*)&kt_s[row * 128 + sl * 8];
        a = __builtin_amdgcn_mfma_f32_16x16x32_bf16(qf[kk], kf, a, 0, 0, 0);
      }
      sc[nf] = a;
    }

    // scale + mask, online softmax (rows owned: r = qt*4+i)
    float sv[4][4];
#pragma unroll
    for (int nf = 0; nf < 4; ++nf) {
      float mk = mask[(size_t)b * S_ + k0 + nf * 16 + ln];
#pragma unroll
      for (int i = 0; i < 4; ++i) sv[nf][i] = sc[nf][i] * scale + mk;
    }
    float fsc[4];
#pragma unroll
    for (int i = 0; i < 4; ++i) {
      float m = fmaxf(fmaxf(sv[0][i], sv[1][i]), fmaxf(sv[2][i], sv[3][i]));
#pragma unroll
      for (int o = 1; o < 16; o <<= 1) m = fmaxf(m, __shfl_xor(m, o));
      float mn = fmaxf(mrun[i], m);
      fsc[i] = __expf(mrun[i] - mn);
      mrun[i] = mn;
    }
#pragma unroll
    for (int i = 0; i < 4; ++i) {
      float t = 0.f;
      int r = qt * 4 + i;
#pragma unroll
      for (int nf = 0; nf < 4; ++nf) {
        float p = __expf(sv[nf][i] - mrun[i]);
        ushort pq = f2bf(p);
        int c = nf * 16 + ln;
        pt[wave][r * 64 + ((c >> 3) ^ (r & 7)) * 8 + (c & 7)] = pq;
        t += bf2f(pq);                      // sum the QUANTIZED P -> exact norm
      }
#pragma unroll
      for (int o = 1; o < 16; o <<= 1) t += __shfl_xor(t, o);
      lrun[i] = lrun[i] * fsc[i] + t;
    }
#pragma unroll
    for (int nfo = 0; nfo < 8; ++nfo)
#pragma unroll
      for (int i = 0; i < 4; ++i) accO[nfo][i] *= fsc[i];

    // PV: accO[16 q][128 d] += P[16][64] * V[64][128]  (same-wave pt, no barrier)
#pragma unroll
    for (int kk2 = 0; kk2 < 2; ++kk2) {
      int psl = (kk2 * 4 + qt) ^ (ln & 7);
      bf16x8 pf = *(const bf16x8*)&pt[wave][ln * 64 + psl * 8];
#pragma unroll
      for (int nfo = 0; nfo < 8; ++nfo) {
        int vrow = nfo * 16 + ln;
        int vsl = (kk2 * 4 + qt) ^ (vrow & 7);
        bf16x8 vf = *(const bf16x8*)&vt_s[vrow * 64 + vsl * 8];
        accO[nfo] = __builtin_amdgcn_mfma_f32_16x16x32_bf16(pf, vf, accO[nfo], 0, 0, 0);
      }
    }
  }

  // epilogue: O (B,S,D) bf16
  float inv[4];
#pragma unroll
  for (int i = 0; i < 4; ++i) inv[i] = 1.f / lrun[i];
#pragma unroll
  for (int nfo = 0; nfo < 8; ++nfo)
#pragma unroll
    for (int i = 0; i < 4; ++i) {
      size_t idx = ((size_t)b * S_ + q0 + qt * 4 + i) * D_ + h * HD_ + nfo * 16 + ln;
      O[idx] = f2bf(accO[nfo][i] * inv[i]);
    }
}

// ---------------- launcher ----------------
extern "C" void kernel_launch(void* const* d_in, const int* in_sizes, int n_in,
                              void* d_out, int out_size, void* d_ws, size_t ws_size,
                              hipStream_t stream)
{
  if (n_in != 8) return;
  if (in_sizes[0] != 8388608) return;       // x  (B,S,D)
  if (in_sizes[3] != 4096)    return;       // mask (B,S)
  if (out_size != 8388608) return;
  if (ws_size < (size_t)96 * 1024 * 1024) return;

  const float* x    = (const float*)d_in[0];
  const float* cosb = (const float*)d_in[1];
  const float* sinb = (const float*)d_in[2];
  const float* mask = (const float*)d_in[3];
  const float* wq   = (const float*)d_in[4];
  const float* wk   = (const float*)d_in[5];
  const float* wv   = (const float*)d_in[6];
  const float* wo   = (const float*)d_in[7];

  char* ws = (char*)d_ws;
  // layout (MB): xb 0..16 | wqb 16..24 | wkb 24..32 | wvb 32..40 | wob 40..48 |
  //              Qb 48..64 | Kb 64..80 | VTb 80..96
  ushort* xb  = (ushort*)(ws);
  ushort* wqb = (ushort*)(ws + 16777216);
  ushort* wkb = (ushort*)(ws + 25165824);
  ushort* wvb = (ushort*)(ws + 33554432);
  ushort* wob = (ushort*)(ws + 41943040);
  ushort* Qb  = (ushort*)(ws + 50331648);
  ushort* Kb  = (ushort*)(ws + 67108864);
  ushort* VTb = (ushort*)(ws + 83886080);
  ushort* AOb = xb;   // reuse: x_bf16 dead after QKV GEMMs

  cvt4<<<8192, 256, 0, stream>>>(x,  xb,  2097152);
  cvt4<<<4096, 256, 0, stream>>>(wq, wqb, 1048576);
  cvt4<<<4096, 256, 0, stream>>>(wk, wkb, 1048576);
  cvt4<<<4096, 256, 0, stream>>>(wv, wvb, 1048576);
  cvt4<<<4096, 256, 0, stream>>>(wo, wob, 1048576);

  dim3 gg(32, 16);   // (M/128, N/128)
  gemm_bt<1><<<gg, 256, 0, stream>>>(xb, wqb, Qb,  4096, 2048, 2048);
  gemm_bt<1><<<gg, 256, 0, stream>>>(xb, wkb, Kb,  4096, 2048, 2048);
  gemm_bt<3><<<gg, 256, 0, stream>>>(xb, wvb, VTb, 4096, 2048, 2048);

  rope_qk<<<32768, 256, 0, stream>>>(Qb, Kb, cosb, sinb);

  flash<<<dim3(32, 32), 256, 0, stream>>>(Qb, Kb, VTb, mask, AOb);

  gemm_bt<0><<<gg, 256, 0, stream>>>(AOb, wob, d_out, 4096, 2048, 2048);
}

// Round 9
// 347.275 us; speedup vs baseline: 35.6729x; 1.1216x over previous
//
#include <hip/hip_runtime.h>

#define B_  2
#define S_  2048
#define D_  2048
#define H_  16
#define HD_ 128

typedef float  f32x4  __attribute__((ext_vector_type(4)));
typedef __bf16 bf16x8 __attribute__((ext_vector_type(8)));

__device__ __forceinline__ void gl16(const void* g, void* l) {
  __builtin_amdgcn_global_load_lds(
      (const __attribute__((address_space(1))) unsigned int*)g,
      (__attribute__((address_space(3))) unsigned int*)l, 16, 0, 0);
}

__device__ __forceinline__ ushort f2bf(float f) {
  union { float f; unsigned u; } v; v.f = f;
  unsigned r = v.u + 0x7FFFu + ((v.u >> 16) & 1u);   // RNE
  return (ushort)(r >> 16);
}
__device__ __forceinline__ float bf2f(ushort b) {
  union { unsigned u; float f; } v; v.u = ((unsigned)b) << 16;
  return v.f;
}
__device__ __forceinline__ f32x4 fzero() {
  f32x4 v; v[0] = 0.f; v[1] = 0.f; v[2] = 0.f; v[3] = 0.f; return v;
}

// ---------------- fp32 -> bf16 convert (vectorized) ----------------
__global__ void cvt4(const float* __restrict__ s, ushort* __restrict__ d, int n4) {
  int i = blockIdx.x * blockDim.x + threadIdx.x;
  if (i >= n4) return;
  float4 v = ((const float4*)s)[i];
  ushort4 o = make_ushort4(f2bf(v.x), f2bf(v.y), f2bf(v.z), f2bf(v.w));
  ((ushort4*)d)[i] = o;
}

// ---------------- MFMA GEMM (m97 recipe, HW-verified) ----------------
// C[m,n] = sum_k A[m,k]*B[n,k], both bf16 row-major (K fast).
// 128x128 tile, BK=32, 4 waves (2x2), global_load_lds w16, dbuf LDS.
// Chunk swizzle: slot = ch ^ ((row>>1)&3), pre-swizzled global source.
// MODE 0: fp32 row-major MxN -> (float*)
// MODE 1: bf16 scatter (B,H,S,HD) -> (ushort*)
// MODE 3: bf16 scatter (B,H,HD,S) -> (ushort*)   (transposed V)
template<int MODE>
__global__ __launch_bounds__(256, 2)
void gemm_bt(const ushort* __restrict__ A, const ushort* __restrict__ Bp,
             void* __restrict__ Cp, int M, int N, int K)
{
  __shared__ __align__(16) ushort lds[2][2][128 * 32];
  const int tid  = threadIdx.x;
  const int wave = tid >> 6, lane = tid & 63;
  const int qt = lane >> 4, ln = lane & 15;
  const int wr = wave >> 1, wc = wave & 1;
  const int bm = blockIdx.x * 128, bn = blockIdx.y * 128;

  f32x4 acc[4][4];
#pragma unroll
  for (int a = 0; a < 4; ++a)
#pragma unroll
    for (int b = 0; b < 4; ++b) acc[a][b] = fzero();

  auto stage = [&](int buf, int kt) {
#pragma unroll
    for (int it = 0; it < 2; ++it) {
      int c = it * 256 + tid;
      int row = c >> 2, ch = c & 3;
      int chs = ch ^ ((row >> 1) & 3);
      gl16(A  + (size_t)(bm + row) * K + kt + chs * 8,
           (void*)&lds[buf][0][(it * 256 + wave * 64) * 8]);
      gl16(Bp + (size_t)(bn + row) * K + kt + chs * 8,
           (void*)&lds[buf][1][(it * 256 + wave * 64) * 8]);
    }
  };

  const int nk = K >> 5;
  stage(0, 0);
  int cur = 0;
  for (int kt = 0; kt < nk; ++kt) {
    __syncthreads();                      // drains vmcnt -> buf[cur] staged
    if (kt + 1 < nk) stage(cur ^ 1, (kt + 1) << 5);
    bf16x8 af[4], bfr[4];
#pragma unroll
    for (int mf = 0; mf < 4; ++mf) {
      int row = wr * 64 + mf * 16 + ln;
      int sl = qt ^ ((row >> 1) & 3);
      af[mf] = *(const bf16x8*)&lds[cur][0][row * 32 + sl * 8];
    }
#pragma unroll
    for (int nf = 0; nf < 4; ++nf) {
      int row = wc * 64 + nf * 16 + ln;
      int sl = qt ^ ((row >> 1) & 3);
      bfr[nf] = *(const bf16x8*)&lds[cur][1][row * 32 + sl * 8];
    }
#pragma unroll
    for (int mf = 0; mf < 4; ++mf)
#pragma unroll
      for (int nf = 0; nf < 4; ++nf)
        acc[mf][nf] = __builtin_amdgcn_mfma_f32_16x16x32_bf16(
            af[mf], bfr[nf], acc[mf][nf], 0, 0, 0);
    cur ^= 1;
  }

  // epilogue: C/D layout col=lane&15, row=(lane>>4)*4+reg  [HW-verified]
#pragma unroll
  for (int mf = 0; mf < 4; ++mf)
#pragma unroll
    for (int nf = 0; nf < 4; ++nf) {
      int m0 = bm + wr * 64 + mf * 16 + qt * 4;
      int n  = bn + wc * 64 + nf * 16 + ln;
#pragma unroll
      for (int i = 0; i < 4; ++i) {
        int m = m0 + i;
        if (MODE == 0) {
          ((float*)Cp)[(size_t)m * N + n] = acc[mf][nf][i];
        } else {
          int b = m >> 11, s = m & 2047;     // m = b*S + s
          int h = n >> 7,  d = n & 127;      // n = h*HD + d
          if (MODE == 1)
            ((ushort*)Cp)[(((size_t)b * H_ + h) * S_ + s) * HD_ + d] = f2bf(acc[mf][nf][i]);
          else
            ((ushort*)Cp)[(((size_t)b * H_ + h) * HD_ + d) * S_ + s] = f2bf(acc[mf][nf][i]);
        }
      }
    }
}

// ---------------- RoPE on Q,K bf16 in (B,H,S,HD), in place ----------------
__global__ void rope_qk(ushort* __restrict__ Q, ushort* __restrict__ Kt,
                        const float* __restrict__ cs, const float* __restrict__ sn)
{
  int t = blockIdx.x * 256 + threadIdx.x;   // 2 * B*H*S * 64 threads
  int d  = t & 63;
  int rr = t >> 6;                          // 0 .. 2*B*H*S-1
  int isk = rr >> 16;                       // B*H*S = 65536
  int bhs = rr & 65535;
  int s = bhs & 2047;
  int b = bhs >> 15;
  ushort* P = isk ? Kt : Q;
  size_t ro = (size_t)bhs * HD_;
  float q0 = bf2f(P[ro + d]), q1 = bf2f(P[ro + d + 64]);
  size_t ci = ((size_t)b * S_ + s) * HD_ + d;
  float c0 = cs[ci], s0 = sn[ci], c1 = cs[ci + 64], s1 = sn[ci + 64];
  P[ro + d]      = f2bf(q0 * c0 - q1 * s0);
  P[ro + d + 64] = f2bf(q1 * c1 + q0 * s1);
}

// ---------------- flash attention: 8 waves, Q-block 128 ----------------
// grid (S/128, B*H), 512 thr = 8 waves x 16 q-rows. KV tiles of 64.
// Same verified per-wave math/swizzles as before; staging amortized over
// 8 waves; launch_bounds(512,4) -> 2 blocks/CU = 16 waves/CU.
// K tile [64][128]: slot = ch ^ (row&7). VT tile [128][64]: slot = ch ^ (d&7).
// P per-wave [16][64]: slot = ch ^ (r&7). LDS 48KB.
__global__ __launch_bounds__(512, 4)
void flash(const ushort* __restrict__ Q, const ushort* __restrict__ Kk,
           const ushort* __restrict__ VT, const float* __restrict__ mask,
           ushort* __restrict__ O)
{
  __shared__ __align__(16) ushort kt_s[64 * 128];
  __shared__ __align__(16) ushort vt_s[128 * 64];
  __shared__ __align__(16) ushort pt[8][16 * 64];

  const int tid = threadIdx.x;
  const int wave = tid >> 6, lane = tid & 63;
  const int qt = lane >> 4, ln = lane & 15;
  const int bh = blockIdx.y, b = bh >> 4, h = bh & 15;
  const size_t base  = (size_t)bh * S_ * HD_;
  const size_t baseT = (size_t)bh * HD_ * S_;
  const int q0 = blockIdx.x * 128 + wave * 16;

  bf16x8 qf[4];
  {
    const ushort* qrow = Q + base + (size_t)(q0 + ln) * HD_;
#pragma unroll
    for (int kk = 0; kk < 4; ++kk)
      qf[kk] = *(const bf16x8*)(qrow + kk * 32 + qt * 8);
  }

  f32x4 accO[8];
#pragma unroll
  for (int i = 0; i < 8; ++i) accO[i] = fzero();
  float mrun[4] = {-1e30f, -1e30f, -1e30f, -1e30f};
  float lrun[4] = {0.f, 0.f, 0.f, 0.f};
  const float scale = 0.08838834764831845f;  // 1/sqrt(128)

  for (int k0 = 0; k0 < S_; k0 += 64) {
    __syncthreads();                         // all waves done with prev tiles
#pragma unroll
    for (int it = 0; it < 2; ++it) {         // K tile: 1024 chunks, 512 thr
      int c = it * 512 + tid;
      int row = c >> 4, ch = c & 15;
      int chs = ch ^ (row & 7);
      gl16(Kk + base + (size_t)(k0 + row) * HD_ + chs * 8,
           (void*)&kt_s[(it * 512 + wave * 64) * 8]);
    }
#pragma unroll
    for (int it = 0; it < 2; ++it) {         // VT tile: 1024 chunks
      int c = it * 512 + tid;
      int row = c >> 3, ch = c & 7;
      int chs = ch ^ (row & 7);
      gl16(VT + baseT + (size_t)row * S_ + k0 + chs * 8,
           (void*)&vt_s[(it * 512 + wave * 64) * 8]);
    }
    __syncthreads();                         // drains vmcnt

    // QK^T: S[q][k] 16x64 per wave
    f32x4 sc[4];
#pragma unroll
    for (int nf = 0; nf < 4; ++nf) {
      f32x4 a = fzero();
      int row = nf * 16 + ln;
#pragma unroll
      for (int kk = 0; kk < 4; ++kk) {
        int sl = (kk * 4 + qt) ^ (row & 7);
        bf16x8 kf = *(const bf16x8*)&kt_s[row * 128 + sl * 8];
        a = __builtin_amdgcn_mfma_f32_16x16x32_bf16(qf[kk], kf, a, 0, 0, 0);
      }
      sc[nf] = a;
    }

    // scale + mask, online softmax (rows owned: r = qt*4+i)
    float sv[4][4];
#pragma unroll
    for (int nf = 0; nf < 4; ++nf) {
      float mk = mask[(size_t)b * S_ + k0 + nf * 16 + ln];
#pragma unroll
      for (int i = 0; i < 4; ++i) sv[nf][i] = sc[nf][i] * scale + mk;
    }
    float fsc[4];
#pragma unroll
    for (int i = 0; i < 4; ++i) {
      float m = fmaxf(fmaxf(sv[0][i], sv[1][i]), fmaxf(sv[2][i], sv[3][i]));
#pragma unroll
      for (int o = 1; o < 16; o <<= 1) m = fmaxf(m, __shfl_xor(m, o));
      float mn = fmaxf(mrun[i], m);
      fsc[i] = __expf(mrun[i] - mn);
      mrun[i] = mn;
    }
#pragma unroll
    for (int i = 0; i < 4; ++i) {
      float t = 0.f;
      int r = qt * 4 + i;
#pragma unroll
      for (int nf = 0; nf < 4; ++nf) {
        float p = __expf(sv[nf][i] - mrun[i]);
        ushort pq = f2bf(p);
        int c = nf * 16 + ln;
        pt[wave][r * 64 + ((c >> 3) ^ (r & 7)) * 8 + (c & 7)] = pq;
        t += bf2f(pq);                      // sum the QUANTIZED P -> exact norm
      }
#pragma unroll
      for (int o = 1; o < 16; o <<= 1) t += __shfl_xor(t, o);
      lrun[i] = lrun[i] * fsc[i] + t;
    }
#pragma unroll
    for (int nfo = 0; nfo < 8; ++nfo)
#pragma unroll
      for (int i = 0; i < 4; ++i) accO[nfo][i] *= fsc[i];

    // PV: accO[16 q][128 d] += P[16][64] * V[64][128]  (same-wave pt, no barrier)
#pragma unroll
    for (int kk2 = 0; kk2 < 2; ++kk2) {
      int psl = (kk2 * 4 + qt) ^ (ln & 7);
      bf16x8 pf = *(const bf16x8*)&pt[wave][ln * 64 + psl * 8];
#pragma unroll
      for (int nfo = 0; nfo < 8; ++nfo) {
        int vrow = nfo * 16 + ln;
        int vsl = (kk2 * 4 + qt) ^ (vrow & 7);
        bf16x8 vf = *(const bf16x8*)&vt_s[vrow * 64 + vsl * 8];
        accO[nfo] = __builtin_amdgcn_mfma_f32_16x16x32_bf16(pf, vf, accO[nfo], 0, 0, 0);
      }
    }
  }

  // epilogue: O (B,S,D) bf16
  float inv[4];
#pragma unroll
  for (int i = 0; i < 4; ++i) inv[i] = 1.f / lrun[i];
#pragma unroll
  for (int nfo = 0; nfo < 8; ++nfo)
#pragma unroll
    for (int i = 0; i < 4; ++i) {
      size_t idx = ((size_t)b * S_ + q0 + qt * 4 + i) * D_ + h * HD_ + nfo * 16 + ln;
      O[idx] = f2bf(accO[nfo][i] * inv[i]);
    }
}

// ---------------- launcher ----------------
extern "C" void kernel_launch(void* const* d_in, const int* in_sizes, int n_in,
                              void* d_out, int out_size, void* d_ws, size_t ws_size,
                              hipStream_t stream)
{
  if (n_in != 8) return;
  if (in_sizes[0] != 8388608) return;       // x  (B,S,D)
  if (in_sizes[3] != 4096)    return;       // mask (B,S)
  if (out_size != 8388608) return;
  if (ws_size < (size_t)96 * 1024 * 1024) return;

  const float* x    = (const float*)d_in[0];
  const float* cosb = (const float*)d_in[1];
  const float* sinb = (const float*)d_in[2];
  const float* mask = (const float*)d_in[3];
  const float* wq   = (const float*)d_in[4];
  const float* wk   = (const float*)d_in[5];
  const float* wv   = (const float*)d_in[6];
  const float* wo   = (const float*)d_in[7];

  char* ws = (char*)d_ws;
  // layout (MB): xb 0..16 | wqb 16..24 | wkb 24..32 | wvb 32..40 | wob 40..48 |
  //              Qb 48..64 | Kb 64..80 | VTb 80..96
  ushort* xb  = (ushort*)(ws);
  ushort* wqb = (ushort*)(ws + 16777216);
  ushort* wkb = (ushort*)(ws + 25165824);
  ushort* wvb = (ushort*)(ws + 33554432);
  ushort* wob = (ushort*)(ws + 41943040);
  ushort* Qb  = (ushort*)(ws + 50331648);
  ushort* Kb  = (ushort*)(ws + 67108864);
  ushort* VTb = (ushort*)(ws + 83886080);
  ushort* AOb = xb;   // reuse: x_bf16 dead after QKV GEMMs

  cvt4<<<8192, 256, 0, stream>>>(x,  xb,  2097152);
  cvt4<<<4096, 256, 0, stream>>>(wq, wqb, 1048576);
  cvt4<<<4096, 256, 0, stream>>>(wk, wkb, 1048576);
  cvt4<<<4096, 256, 0, stream>>>(wv, wvb, 1048576);
  cvt4<<<4096, 256, 0, stream>>>(wo, wob, 1048576);

  dim3 gg(32, 16);   // (M/128, N/128)
  gemm_bt<1><<<gg, 256, 0, stream>>>(xb, wqb, Qb,  4096, 2048, 2048);
  gemm_bt<1><<<gg, 256, 0, stream>>>(xb, wkb, Kb,  4096, 2048, 2048);
  gemm_bt<3><<<gg, 256, 0, stream>>>(xb, wvb, VTb, 4096, 2048, 2048);

  rope_qk<<<32768, 256, 0, stream>>>(Qb, Kb, cosb, sinb);

  flash<<<dim3(16, 32), 512, 0, stream>>>(Qb, Kb, VTb, mask, AOb);

  gemm_bt<0><<<gg, 256, 0, stream>>>(AOb, wob, d_out, 4096, 2048, 2048);
}

// Round 10
// 338.569 us; speedup vs baseline: 36.5902x; 1.0257x over previous
//
#include <hip/hip_runtime.h>

#define B_  2
#define S_  2048
#define D_  2048
#define H_  16
#define HD_ 128

typedef float  f32x4  __attribute__((ext_vector_type(4)));
typedef __bf16 bf16x8 __attribute__((ext_vector_type(8)));

__device__ __forceinline__ void gl16(const void* g, void* l) {
  __builtin_amdgcn_global_load_lds(
      (const __attribute__((address_space(1))) unsigned int*)g,
      (__attribute__((address_space(3))) unsigned int*)l, 16, 0, 0);
}

__device__ __forceinline__ ushort f2bf(float f) {
  union { float f; unsigned u; } v; v.f = f;
  unsigned r = v.u + 0x7FFFu + ((v.u >> 16) & 1u);   // RNE
  return (ushort)(r >> 16);
}
__device__ __forceinline__ float bf2f(ushort b) {
  union { unsigned u; float f; } v; v.u = ((unsigned)b) << 16;
  return v.f;
}
__device__ __forceinline__ f32x4 fzero() {
  f32x4 v; v[0] = 0.f; v[1] = 0.f; v[2] = 0.f; v[3] = 0.f; return v;
}

// ---------------- fp32 -> bf16 convert (vectorized) ----------------
__global__ void cvt4(const float* __restrict__ s, ushort* __restrict__ d, int n4) {
  int i = blockIdx.x * blockDim.x + threadIdx.x;
  if (i >= n4) return;
  float4 v = ((const float4*)s)[i];
  ushort4 o = make_ushort4(f2bf(v.x), f2bf(v.y), f2bf(v.z), f2bf(v.w));
  ((ushort4*)d)[i] = o;
}

// ---------------- MFMA GEMM (m97 recipe, HW-verified) ----------------
// C[m,n] = sum_k A[m,k]*B[n,k], both bf16 row-major (K fast).
// 128x128 tile, BK=32, 4 waves (2x2), global_load_lds w16, dbuf LDS.
// MODE 0: fp32 row-major MxN -> (float*)
// MODE 1: bf16 scatter (B,H,S,HD) -> (ushort*)
// MODE 3: bf16 scatter (B,H,HD,S) -> (ushort*)   (transposed V)
template<int MODE>
__global__ __launch_bounds__(256, 2)
void gemm_bt(const ushort* __restrict__ A, const ushort* __restrict__ Bp,
             void* __restrict__ Cp, int M, int N, int K)
{
  __shared__ __align__(16) ushort lds[2][2][128 * 32];
  const int tid  = threadIdx.x;
  const int wave = tid >> 6, lane = tid & 63;
  const int qt = lane >> 4, ln = lane & 15;
  const int wr = wave >> 1, wc = wave & 1;
  const int bm = blockIdx.x * 128, bn = blockIdx.y * 128;

  f32x4 acc[4][4];
#pragma unroll
  for (int a = 0; a < 4; ++a)
#pragma unroll
    for (int b = 0; b < 4; ++b) acc[a][b] = fzero();

  auto stage = [&](int buf, int kt) {
#pragma unroll
    for (int it = 0; it < 2; ++it) {
      int c = it * 256 + tid;
      int row = c >> 2, ch = c & 3;
      int chs = ch ^ ((row >> 1) & 3);
      gl16(A  + (size_t)(bm + row) * K + kt + chs * 8,
           (void*)&lds[buf][0][(it * 256 + wave * 64) * 8]);
      gl16(Bp + (size_t)(bn + row) * K + kt + chs * 8,
           (void*)&lds[buf][1][(it * 256 + wave * 64) * 8]);
    }
  };

  const int nk = K >> 5;
  stage(0, 0);
  int cur = 0;
  for (int kt = 0; kt < nk; ++kt) {
    __syncthreads();                      // drains vmcnt -> buf[cur] staged
    if (kt + 1 < nk) stage(cur ^ 1, (kt + 1) << 5);
    bf16x8 af[4], bfr[4];
#pragma unroll
    for (int mf = 0; mf < 4; ++mf) {
      int row = wr * 64 + mf * 16 + ln;
      int sl = qt ^ ((row >> 1) & 3);
      af[mf] = *(const bf16x8*)&lds[cur][0][row * 32 + sl * 8];
    }
#pragma unroll
    for (int nf = 0; nf < 4; ++nf) {
      int row = wc * 64 + nf * 16 + ln;
      int sl = qt ^ ((row >> 1) & 3);
      bfr[nf] = *(const bf16x8*)&lds[cur][1][row * 32 + sl * 8];
    }
#pragma unroll
    for (int mf = 0; mf < 4; ++mf)
#pragma unroll
      for (int nf = 0; nf < 4; ++nf)
        acc[mf][nf] = __builtin_amdgcn_mfma_f32_16x16x32_bf16(
            af[mf], bfr[nf], acc[mf][nf], 0, 0, 0);
    cur ^= 1;
  }

  // epilogue: C/D layout col=lane&15, row=(lane>>4)*4+reg  [HW-verified]
#pragma unroll
  for (int mf = 0; mf < 4; ++mf)
#pragma unroll
    for (int nf = 0; nf < 4; ++nf) {
      int m0 = bm + wr * 64 + mf * 16 + qt * 4;
      int n  = bn + wc * 64 + nf * 16 + ln;
#pragma unroll
      for (int i = 0; i < 4; ++i) {
        int m = m0 + i;
        if (MODE == 0) {
          ((float*)Cp)[(size_t)m * N + n] = acc[mf][nf][i];
        } else {
          int b = m >> 11, s = m & 2047;     // m = b*S + s
          int h = n >> 7,  d = n & 127;      // n = h*HD + d
          if (MODE == 1)
            ((ushort*)Cp)[(((size_t)b * H_ + h) * S_ + s) * HD_ + d] = f2bf(acc[mf][nf][i]);
          else
            ((ushort*)Cp)[(((size_t)b * H_ + h) * HD_ + d) * S_ + s] = f2bf(acc[mf][nf][i]);
        }
      }
    }
}

// ---------------- RoPE on Q,K bf16 in (B,H,S,HD), in place ----------------
__global__ void rope_qk(ushort* __restrict__ Q, ushort* __restrict__ Kt,
                        const float* __restrict__ cs, const float* __restrict__ sn)
{
  int t = blockIdx.x * 256 + threadIdx.x;   // 2 * B*H*S * 64 threads
  int d  = t & 63;
  int rr = t >> 6;                          // 0 .. 2*B*H*S-1
  int isk = rr >> 16;                       // B*H*S = 65536
  int bhs = rr & 65535;
  int s = bhs & 2047;
  int b = bhs >> 15;
  ushort* P = isk ? Kt : Q;
  size_t ro = (size_t)bhs * HD_;
  float q0 = bf2f(P[ro + d]), q1 = bf2f(P[ro + d + 64]);
  size_t ci = ((size_t)b * S_ + s) * HD_ + d;
  float c0 = cs[ci], s0 = sn[ci], c1 = cs[ci + 64], s1 = sn[ci + 64];
  P[ro + d]      = f2bf(q0 * c0 - q1 * s0);
  P[ro + d + 64] = f2bf(q1 * c1 + q0 * s1);
}

// ---------------- flash attention: 8 waves, Q-block 128, dbuf K/V ----------
// grid (B*H, S/128): bh = blockIdx.x -> all q-blocks of a head land on one
// XCD (32 % 8 == 0) for K/V L2 residency. 512 thr = 8 waves x 16 q-rows.
// KV tiles of 64, DOUBLE-BUFFERED: stage(t+1) issued before compute(t)
// (m97 pattern), so load latency hides under MFMA+softmax. LDS 80KB ->
// 2 blocks/CU. setprio(1) around MFMA clusters (T5).
// K tile [64][128]: slot = ch ^ (row&7). VT tile [128][64]: slot = ch ^ (d&7).
// P per-wave [16][64]: slot = ch ^ (r&7).
__global__ __launch_bounds__(512, 4)
void flash(const ushort* __restrict__ Q, const ushort* __restrict__ Kk,
           const ushort* __restrict__ VT, const float* __restrict__ mask,
           ushort* __restrict__ O)
{
  __shared__ __align__(16) ushort kt_s[2][64 * 128];
  __shared__ __align__(16) ushort vt_s[2][128 * 64];
  __shared__ __align__(16) ushort pt[8][16 * 64];

  const int tid = threadIdx.x;
  const int wave = tid >> 6, lane = tid & 63;
  const int qt = lane >> 4, ln = lane & 15;
  const int bh = blockIdx.x, b = bh >> 4, h = bh & 15;
  const size_t base  = (size_t)bh * S_ * HD_;
  const size_t baseT = (size_t)bh * HD_ * S_;
  const int q0 = blockIdx.y * 128 + wave * 16;

  bf16x8 qf[4];
  {
    const ushort* qrow = Q + base + (size_t)(q0 + ln) * HD_;
#pragma unroll
    for (int kk = 0; kk < 4; ++kk)
      qf[kk] = *(const bf16x8*)(qrow + kk * 32 + qt * 8);
  }

  f32x4 accO[8];
#pragma unroll
  for (int i = 0; i < 8; ++i) accO[i] = fzero();
  float mrun[4] = {-1e30f, -1e30f, -1e30f, -1e30f};
  float lrun[4] = {0.f, 0.f, 0.f, 0.f};
  const float scale = 0.08838834764831845f;  // 1/sqrt(128)

  auto stageKV = [&](int buf, int k0) {
#pragma unroll
    for (int it = 0; it < 2; ++it) {         // K tile: 1024 chunks, 512 thr
      int c = it * 512 + tid;
      int row = c >> 4, ch = c & 15;
      int chs = ch ^ (row & 7);
      gl16(Kk + base + (size_t)(k0 + row) * HD_ + chs * 8,
           (void*)&kt_s[buf][(it * 512 + wave * 64) * 8]);
    }
#pragma unroll
    for (int it = 0; it < 2; ++it) {         // VT tile: 1024 chunks
      int c = it * 512 + tid;
      int row = c >> 3, ch = c & 7;
      int chs = ch ^ (row & 7);
      gl16(VT + baseT + (size_t)row * S_ + k0 + chs * 8,
           (void*)&vt_s[buf][(it * 512 + wave * 64) * 8]);
    }
  };

  stageKV(0, 0);
  int cur = 0;
  for (int k0 = 0; k0 < S_; k0 += 64) {
    __syncthreads();                         // drains vmcnt: buf[cur] staged;
                                             // all waves done reading buf[cur^1]
    if (k0 + 64 < S_) stageKV(cur ^ 1, k0 + 64);  // flies under compute below

    // QK^T: S[q][k] 16x64 per wave
    f32x4 sc[4];
    __builtin_amdgcn_s_setprio(1);
#pragma unroll
    for (int nf = 0; nf < 4; ++nf) {
      f32x4 a = fzero();
      int row = nf * 16 + ln;
#pragma unroll
      for (int kk = 0; kk < 4; ++kk) {
        int sl = (kk * 4 + qt) ^ (row & 7);
        bf16x8 kf = *(const bf16x8*)&kt_s[cur][row * 128 + sl * 8];
        a = __builtin_amdgcn_mfma_f32_16x16x32_bf16(qf[kk], kf, a, 0, 0, 0);
      }
      sc[nf] = a;
    }
    __builtin_amdgcn_s_setprio(0);

    // scale + mask, online softmax (rows owned: r = qt*4+i)
    float sv[4][4];
#pragma unroll
    for (int nf = 0; nf < 4; ++nf) {
      float mk = mask[(size_t)b * S_ + k0 + nf * 16 + ln];
#pragma unroll
      for (int i = 0; i < 4; ++i) sv[nf][i] = sc[nf][i] * scale + mk;
    }
    float fsc[4];
#pragma unroll
    for (int i = 0; i < 4; ++i) {
      float m = fmaxf(fmaxf(sv[0][i], sv[1][i]), fmaxf(sv[2][i], sv[3][i]));
#pragma unroll
      for (int o = 1; o < 16; o <<= 1) m = fmaxf(m, __shfl_xor(m, o));
      float mn = fmaxf(mrun[i], m);
      fsc[i] = __expf(mrun[i] - mn);
      mrun[i] = mn;
    }
#pragma unroll
    for (int i = 0; i < 4; ++i) {
      float t = 0.f;
      int r = qt * 4 + i;
#pragma unroll
      for (int nf = 0; nf < 4; ++nf) {
        float p = __expf(sv[nf][i] - mrun[i]);
        ushort pq = f2bf(p);
        int c = nf * 16 + ln;
        pt[wave][r * 64 + ((c >> 3) ^ (r & 7)) * 8 + (c & 7)] = pq;
        t += bf2f(pq);                      // sum the QUANTIZED P -> exact norm
      }
#pragma unroll
      for (int o = 1; o < 16; o <<= 1) t += __shfl_xor(t, o);
      lrun[i] = lrun[i] * fsc[i] + t;
    }
#pragma unroll
    for (int nfo = 0; nfo < 8; ++nfo)
#pragma unroll
      for (int i = 0; i < 4; ++i) accO[nfo][i] *= fsc[i];

    // PV: accO[16 q][128 d] += P[16][64] * V[64][128]  (same-wave pt)
    __builtin_amdgcn_s_setprio(1);
#pragma unroll
    for (int kk2 = 0; kk2 < 2; ++kk2) {
      int psl = (kk2 * 4 + qt) ^ (ln & 7);
      bf16x8 pf = *(const bf16x8*)&pt[wave][ln * 64 + psl * 8];
#pragma unroll
      for (int nfo = 0; nfo < 8; ++nfo) {
        int vrow = nfo * 16 + ln;
        int vsl = (kk2 * 4 + qt) ^ (vrow & 7);
        bf16x8 vf = *(const bf16x8*)&vt_s[cur][vrow * 64 + vsl * 8];
        accO[nfo] = __builtin_amdgcn_mfma_f32_16x16x32_bf16(pf, vf, accO[nfo], 0, 0, 0);
      }
    }
    __builtin_amdgcn_s_setprio(0);
    cur ^= 1;
  }

  // epilogue: O (B,S,D) bf16
  float inv[4];
#pragma unroll
  for (int i = 0; i < 4; ++i) inv[i] = 1.f / lrun[i];
#pragma unroll
  for (int nfo = 0; nfo < 8; ++nfo)
#pragma unroll
    for (int i = 0; i < 4; ++i) {
      size_t idx = ((size_t)b * S_ + q0 + qt * 4 + i) * D_ + h * HD_ + nfo * 16 + ln;
      O[idx] = f2bf(accO[nfo][i] * inv[i]);
    }
}

// ---------------- launcher ----------------
extern "C" void kernel_launch(void* const* d_in, const int* in_sizes, int n_in,
                              void* d_out, int out_size, void* d_ws, size_t ws_size,
                              hipStream_t stream)
{
  if (n_in != 8) return;
  if (in_sizes[0] != 8388608) return;       // x  (B,S,D)
  if (in_sizes[3] != 4096)    return;       // mask (B,S)
  if (out_size != 8388608) return;
  if (ws_size < (size_t)96 * 1024 * 1024) return;

  const float* x    = (const float*)d_in[0];
  const float* cosb = (const float*)d_in[1];
  const float* sinb = (const float*)d_in[2];
  const float* mask = (const float*)d_in[3];
  const float* wq   = (const float*)d_in[4];
  const float* wk   = (const float*)d_in[5];
  const float* wv   = (const float*)d_in[6];
  const float* wo   = (const float*)d_in[7];

  char* ws = (char*)d_ws;
  // layout (MB): xb 0..16 | wqb 16..24 | wkb 24..32 | wvb 32..40 | wob 40..48 |
  //              Qb 48..64 | Kb 64..80 | VTb 80..96
  ushort* xb  = (ushort*)(ws);
  ushort* wqb = (ushort*)(ws + 16777216);
  ushort* wkb = (ushort*)(ws + 25165824);
  ushort* wvb = (ushort*)(ws + 33554432);
  ushort* wob = (ushort*)(ws + 41943040);
  ushort* Qb  = (ushort*)(ws + 50331648);
  ushort* Kb  = (ushort*)(ws + 67108864);
  ushort* VTb = (ushort*)(ws + 83886080);
  ushort* AOb = xb;   // reuse: x_bf16 dead after QKV GEMMs

  cvt4<<<8192, 256, 0, stream>>>(x,  xb,  2097152);
  cvt4<<<4096, 256, 0, stream>>>(wq, wqb, 1048576);
  cvt4<<<4096, 256, 0, stream>>>(wk, wkb, 1048576);
  cvt4<<<4096, 256, 0, stream>>>(wv, wvb, 1048576);
  cvt4<<<4096, 256, 0, stream>>>(wo, wob, 1048576);

  dim3 gg(32, 16);   // (M/128, N/128)
  gemm_bt<1><<<gg, 256, 0, stream>>>(xb, wqb, Qb,  4096, 2048, 2048);
  gemm_bt<1><<<gg, 256, 0, stream>>>(xb, wkb, Kb,  4096, 2048, 2048);
  gemm_bt<3><<<gg, 256, 0, stream>>>(xb, wvb, VTb, 4096, 2048, 2048);

  rope_qk<<<32768, 256, 0, stream>>>(Qb, Kb, cosb, sinb);

  flash<<<dim3(32, 16), 512, 0, stream>>>(Qb, Kb, VTb, mask, AOb);

  gemm_bt<0><<<gg, 256, 0, stream>>>(AOb, wob, d_out, 4096, 2048, 2048);
}

// Round 12
// 317.991 us; speedup vs baseline: 38.9581x; 1.0647x over previous
//
#include <hip/hip_runtime.h>

#define B_  2
#define S_  2048
#define D_  2048
#define H_  16
#define HD_ 128

typedef float  f32x4  __attribute__((ext_vector_type(4)));
typedef __bf16 bf16x8 __attribute__((ext_vector_type(8)));

__device__ __forceinline__ void gl16(const void* g, void* l) {
  __builtin_amdgcn_global_load_lds(
      (const __attribute__((address_space(1))) unsigned int*)g,
      (__attribute__((address_space(3))) unsigned int*)l, 16, 0, 0);
}

__device__ __forceinline__ ushort f2bf(float f) {
  union { float f; unsigned u; } v; v.f = f;
  unsigned r = v.u + 0x7FFFu + ((v.u >> 16) & 1u);   // RNE
  return (ushort)(r >> 16);
}
__device__ __forceinline__ float bf2f(ushort b) {
  union { unsigned u; float f; } v; v.u = ((unsigned)b) << 16;
  return v.f;
}
__device__ __forceinline__ f32x4 fzero() {
  f32x4 v; v[0] = 0.f; v[1] = 0.f; v[2] = 0.f; v[3] = 0.f; return v;
}
// raw v_exp_f32: D = 2^S0  (HIP has no __exp2f; use the amdgcn builtin)
__device__ __forceinline__ float exp2x(float x) {
  return __builtin_amdgcn_exp2f(x);
}

// ---------------- fp32 -> bf16 convert (vectorized) ----------------
__global__ void cvt4(const float* __restrict__ s, ushort* __restrict__ d, int n4) {
  int i = blockIdx.x * blockDim.x + threadIdx.x;
  if (i >= n4) return;
  float4 v = ((const float4*)s)[i];
  ushort4 o = make_ushort4(f2bf(v.x), f2bf(v.y), f2bf(v.z), f2bf(v.w));
  ((ushort4*)d)[i] = o;
}

// ---------------- MFMA GEMM (m97 recipe, HW-verified) ----------------
// C[m,n] = sum_k A[m,k]*B[n,k], both bf16 row-major (K fast).
// 128x128 tile, BK=32, 4 waves (2x2), global_load_lds w16, dbuf LDS.
// MODE 0: fp32 row-major MxN -> (float*)
// MODE 1: bf16 scatter (B,H,S,HD) -> (ushort*)
// MODE 3: bf16 scatter (B,H,HD,S) -> (ushort*)   (transposed V)
template<int MODE>
__global__ __launch_bounds__(256, 2)
void gemm_bt(const ushort* __restrict__ A, const ushort* __restrict__ Bp,
             void* __restrict__ Cp, int M, int N, int K)
{
  __shared__ __align__(16) ushort lds[2][2][128 * 32];
  const int tid  = threadIdx.x;
  const int wave = tid >> 6, lane = tid & 63;
  const int qt = lane >> 4, ln = lane & 15;
  const int wr = wave >> 1, wc = wave & 1;
  const int bm = blockIdx.x * 128, bn = blockIdx.y * 128;

  f32x4 acc[4][4];
#pragma unroll
  for (int a = 0; a < 4; ++a)
#pragma unroll
    for (int b = 0; b < 4; ++b) acc[a][b] = fzero();

  auto stage = [&](int buf, int kt) {
#pragma unroll
    for (int it = 0; it < 2; ++it) {
      int c = it * 256 + tid;
      int row = c >> 2, ch = c & 3;
      int chs = ch ^ ((row >> 1) & 3);
      gl16(A  + (size_t)(bm + row) * K + kt + chs * 8,
           (void*)&lds[buf][0][(it * 256 + wave * 64) * 8]);
      gl16(Bp + (size_t)(bn + row) * K + kt + chs * 8,
           (void*)&lds[buf][1][(it * 256 + wave * 64) * 8]);
    }
  };

  const int nk = K >> 5;
  stage(0, 0);
  int cur = 0;
  for (int kt = 0; kt < nk; ++kt) {
    __syncthreads();                      // drains vmcnt -> buf[cur] staged
    if (kt + 1 < nk) stage(cur ^ 1, (kt + 1) << 5);
    bf16x8 af[4], bfr[4];
#pragma unroll
    for (int mf = 0; mf < 4; ++mf) {
      int row = wr * 64 + mf * 16 + ln;
      int sl = qt ^ ((row >> 1) & 3);
      af[mf] = *(const bf16x8*)&lds[cur][0][row * 32 + sl * 8];
    }
#pragma unroll
    for (int nf = 0; nf < 4; ++nf) {
      int row = wc * 64 + nf * 16 + ln;
      int sl = qt ^ ((row >> 1) & 3);
      bfr[nf] = *(const bf16x8*)&lds[cur][1][row * 32 + sl * 8];
    }
#pragma unroll
    for (int mf = 0; mf < 4; ++mf)
#pragma unroll
      for (int nf = 0; nf < 4; ++nf)
        acc[mf][nf] = __builtin_amdgcn_mfma_f32_16x16x32_bf16(
            af[mf], bfr[nf], acc[mf][nf], 0, 0, 0);
    cur ^= 1;
  }

  // epilogue: C/D layout col=lane&15, row=(lane>>4)*4+reg  [HW-verified]
#pragma unroll
  for (int mf = 0; mf < 4; ++mf)
#pragma unroll
    for (int nf = 0; nf < 4; ++nf) {
      int m0 = bm + wr * 64 + mf * 16 + qt * 4;
      int n  = bn + wc * 64 + nf * 16 + ln;
#pragma unroll
      for (int i = 0; i < 4; ++i) {
        int m = m0 + i;
        if (MODE == 0) {
          ((float*)Cp)[(size_t)m * N + n] = acc[mf][nf][i];
        } else {
          int b = m >> 11, s = m & 2047;     // m = b*S + s
          int h = n >> 7,  d = n & 127;      // n = h*HD + d
          if (MODE == 1)
            ((ushort*)Cp)[(((size_t)b * H_ + h) * S_ + s) * HD_ + d] = f2bf(acc[mf][nf][i]);
          else
            ((ushort*)Cp)[(((size_t)b * H_ + h) * HD_ + d) * S_ + s] = f2bf(acc[mf][nf][i]);
        }
      }
    }
}

// ---------------- RoPE on Q,K bf16 in (B,H,S,HD), in place ----------------
__global__ void rope_qk(ushort* __restrict__ Q, ushort* __restrict__ Kt,
                        const float* __restrict__ cs, const float* __restrict__ sn)
{
  int t = blockIdx.x * 256 + threadIdx.x;   // 2 * B*H*S * 64 threads
  int d  = t & 63;
  int rr = t >> 6;                          // 0 .. 2*B*H*S-1
  int isk = rr >> 16;                       // B*H*S = 65536
  int bhs = rr & 65535;
  int s = bhs & 2047;
  int b = bhs >> 15;
  ushort* P = isk ? Kt : Q;
  size_t ro = (size_t)bhs * HD_;
  float q0 = bf2f(P[ro + d]), q1 = bf2f(P[ro + d + 64]);
  size_t ci = ((size_t)b * S_ + s) * HD_ + d;
  float c0 = cs[ci], s0 = sn[ci], c1 = cs[ci + 64], s1 = sn[ci + 64];
  P[ro + d]      = f2bf(q0 * c0 - q1 * s0);
  P[ro + d + 64] = f2bf(q1 * c1 + q0 * s1);
}

// ---------------- flash attention: 8 waves, Q-block 128, dbuf K/V ----------
// grid (B*H, S/128) -> head-per-XCD K/V L2 residency. 512 thr = 8 waves.
// Softmax in exp2 domain (log2e folded into scale+mask), per-lane partial
// lrun (cross-lane reduce deferred to epilogue), native __bf16 casts,
// defer-max rescale (THR=8 in log2 domain, wave-voted).
// K tile [64][128]: slot = ch ^ (row&7). VT tile [128][64]: slot = ch ^ (d&7).
// P per-wave [16][64]: slot = ch ^ (r&7). LDS 80KB -> 2 blocks/CU.
__global__ __launch_bounds__(512, 4)
void flash(const ushort* __restrict__ Q, const ushort* __restrict__ Kk,
           const ushort* __restrict__ VT, const float* __restrict__ mask,
           ushort* __restrict__ O)
{
  __shared__ __align__(16) ushort kt_s[2][64 * 128];
  __shared__ __align__(16) ushort vt_s[2][128 * 64];
  __shared__ __align__(16) ushort pt[8][16 * 64];

  const int tid = threadIdx.x;
  const int wave = tid >> 6, lane = tid & 63;
  const int qt = lane >> 4, ln = lane & 15;
  const int bh = blockIdx.x, b = bh >> 4, h = bh & 15;
  const size_t base  = (size_t)bh * S_ * HD_;
  const size_t baseT = (size_t)bh * HD_ * S_;
  const int q0 = blockIdx.y * 128 + wave * 16;
  const float L2E = 1.4426950408889634f;

  bf16x8 qf[4];
  {
    const ushort* qrow = Q + base + (size_t)(q0 + ln) * HD_;
#pragma unroll
    for (int kk = 0; kk < 4; ++kk)
      qf[kk] = *(const bf16x8*)(qrow + kk * 32 + qt * 8);
  }

  f32x4 accO[8];
#pragma unroll
  for (int i = 0; i < 8; ++i) accO[i] = fzero();
  float mrun[4] = {-1e30f, -1e30f, -1e30f, -1e30f};
  float lrun[4] = {0.f, 0.f, 0.f, 0.f};   // per-lane partial (reduced at end)
  const float scale2 = 0.08838834764831845f * L2E;  // (1/sqrt(128))*log2e

  auto stageKV = [&](int buf, int k0) {
#pragma unroll
    for (int it = 0; it < 2; ++it) {         // K tile: 1024 chunks, 512 thr
      int c = it * 512 + tid;
      int row = c >> 4, ch = c & 15;
      int chs = ch ^ (row & 7);
      gl16(Kk + base + (size_t)(k0 + row) * HD_ + chs * 8,
           (void*)&kt_s[buf][(it * 512 + wave * 64) * 8]);
    }
#pragma unroll
    for (int it = 0; it < 2; ++it) {         // VT tile: 1024 chunks
      int c = it * 512 + tid;
      int row = c >> 3, ch = c & 7;
      int chs = ch ^ (row & 7);
      gl16(VT + baseT + (size_t)row * S_ + k0 + chs * 8,
           (void*)&vt_s[buf][(it * 512 + wave * 64) * 8]);
    }
  };

  stageKV(0, 0);
  int cur = 0;
  for (int k0 = 0; k0 < S_; k0 += 64) {
    __syncthreads();                         // buf[cur] staged; prev reads done
    if (k0 + 64 < S_) stageKV(cur ^ 1, k0 + 64);  // flies under compute below

    // QK^T: S[q][k] 16x64 per wave
    f32x4 sc[4];
    __builtin_amdgcn_s_setprio(1);
#pragma unroll
    for (int nf = 0; nf < 4; ++nf) {
      f32x4 a = fzero();
      int row = nf * 16 + ln;
#pragma unroll
      for (int kk = 0; kk < 4; ++kk) {
        int sl = (kk * 4 + qt) ^ (row & 7);
        bf16x8 kf = *(const bf16x8*)&kt_s[cur][row * 128 + sl * 8];
        a = __builtin_amdgcn_mfma_f32_16x16x32_bf16(qf[kk], kf, a, 0, 0, 0);
      }
      sc[nf] = a;
    }
    __builtin_amdgcn_s_setprio(0);

    // scale + mask in log2 domain; online softmax (rows owned: r = qt*4+i)
    float sv[4][4];
#pragma unroll
    for (int nf = 0; nf < 4; ++nf) {
      float mk = mask[(size_t)b * S_ + k0 + nf * 16 + ln] * L2E;
#pragma unroll
      for (int i = 0; i < 4; ++i) sv[nf][i] = sc[nf][i] * scale2 + mk;
    }
    // row max of this tile
    float pmax[4];
#pragma unroll
    for (int i = 0; i < 4; ++i) {
      float m = fmaxf(fmaxf(sv[0][i], sv[1][i]), fmaxf(sv[2][i], sv[3][i]));
#pragma unroll
      for (int o = 1; o < 16; o <<= 1) m = fmaxf(m, __shfl_xor(m, o));
      pmax[i] = m;
    }
    // defer-max: rescale only if some row grew past THR=8 (exp2 domain)
    bool need = (pmax[0] > mrun[0] + 8.f) | (pmax[1] > mrun[1] + 8.f) |
                (pmax[2] > mrun[2] + 8.f) | (pmax[3] > mrun[3] + 8.f);
    if (__any(need)) {
#pragma unroll
      for (int i = 0; i < 4; ++i) {
        float mn = fmaxf(mrun[i], pmax[i]);
        float fsc = exp2x(mrun[i] - mn);
        mrun[i] = mn;
        lrun[i] *= fsc;
#pragma unroll
        for (int nfo = 0; nfo < 8; ++nfo) accO[nfo][i] *= fsc;
      }
    }
    // P = exp2(sv - mrun)  (bounded by 2^8), quantize bf16, per-lane sum
#pragma unroll
    for (int i = 0; i < 4; ++i) {
      float t = 0.f;
      int r = qt * 4 + i;
#pragma unroll
      for (int nf = 0; nf < 4; ++nf) {
        float p = exp2x(sv[nf][i] - mrun[i]);
        __bf16 pb = (__bf16)p;               // HW cvt, RNE
        int c = nf * 16 + ln;
        *(__bf16*)&pt[wave][r * 64 + ((c >> 3) ^ (r & 7)) * 8 + (c & 7)] = pb;
        t += (float)pb;                      // sum QUANTIZED P -> exact norm
      }
      lrun[i] += t;                          // per-lane partial
    }

    // PV: accO[16 q][128 d] += P[16][64] * V[64][128]  (same-wave pt)
    __builtin_amdgcn_s_setprio(1);
#pragma unroll
    for (int kk2 = 0; kk2 < 2; ++kk2) {
      int psl = (kk2 * 4 + qt) ^ (ln & 7);
      bf16x8 pf = *(const bf16x8*)&pt[wave][ln * 64 + psl * 8];
#pragma unroll
      for (int nfo = 0; nfo < 8; ++nfo) {
        int vrow = nfo * 16 + ln;
        int vsl = (kk2 * 4 + qt) ^ (vrow & 7);
        bf16x8 vf = *(const bf16x8*)&vt_s[cur][vrow * 64 + vsl * 8];
        accO[nfo] = __builtin_amdgcn_mfma_f32_16x16x32_bf16(pf, vf, accO[nfo], 0, 0, 0);
      }
    }
    __builtin_amdgcn_s_setprio(0);
    cur ^= 1;
  }

  // epilogue: cross-lane reduce of lrun partials, then O (B,S,D) bf16
  float inv[4];
#pragma unroll
  for (int i = 0; i < 4; ++i) {
    float t = lrun[i];
#pragma unroll
    for (int o = 1; o < 16; o <<= 1) t += __shfl_xor(t, o);
    inv[i] = 1.f / t;
  }
#pragma unroll
  for (int nfo = 0; nfo < 8; ++nfo)
#pragma unroll
    for (int i = 0; i < 4; ++i) {
      size_t idx = ((size_t)b * S_ + q0 + qt * 4 + i) * D_ + h * HD_ + nfo * 16 + ln;
      O[idx] = f2bf(accO[nfo][i] * inv[i]);
    }
}

// ---------------- launcher ----------------
extern "C" void kernel_launch(void* const* d_in, const int* in_sizes, int n_in,
                              void* d_out, int out_size, void* d_ws, size_t ws_size,
                              hipStream_t stream)
{
  if (n_in != 8) return;
  if (in_sizes[0] != 8388608) return;       // x  (B,S,D)
  if (in_sizes[3] != 4096)    return;       // mask (B,S)
  if (out_size != 8388608) return;
  if (ws_size < (size_t)96 * 1024 * 1024) return;

  const float* x    = (const float*)d_in[0];
  const float* cosb = (const float*)d_in[1];
  const float* sinb = (const float*)d_in[2];
  const float* mask = (const float*)d_in[3];
  const float* wq   = (const float*)d_in[4];
  const float* wk   = (const float*)d_in[5];
  const float* wv   = (const float*)d_in[6];
  const float* wo   = (const float*)d_in[7];

  char* ws = (char*)d_ws;
  // layout (MB): xb 0..16 | wqb 16..24 | wkb 24..32 | wvb 32..40 | wob 40..48 |
  //              Qb 48..64 | Kb 64..80 | VTb 80..96
  ushort* xb  = (ushort*)(ws);
  ushort* wqb = (ushort*)(ws + 16777216);
  ushort* wkb = (ushort*)(ws + 25165824);
  ushort* wvb = (ushort*)(ws + 33554432);
  ushort* wob = (ushort*)(ws + 41943040);
  ushort* Qb  = (ushort*)(ws + 50331648);
  ushort* Kb  = (ushort*)(ws + 67108864);
  ushort* VTb = (ushort*)(ws + 83886080);
  ushort* AOb = xb;   // reuse: x_bf16 dead after QKV GEMMs

  cvt4<<<8192, 256, 0, stream>>>(x,  xb,  2097152);
  cvt4<<<4096, 256, 0, stream>>>(wq, wqb, 1048576);
  cvt4<<<4096, 256, 0, stream>>>(wk, wkb, 1048576);
  cvt4<<<4096, 256, 0, stream>>>(wv, wvb, 1048576);
  cvt4<<<4096, 256, 0, stream>>>(wo, wob, 1048576);

  dim3 gg(32, 16);   // (M/128, N/128)
  gemm_bt<1><<<gg, 256, 0, stream>>>(xb, wqb, Qb,  4096, 2048, 2048);
  gemm_bt<1><<<gg, 256, 0, stream>>>(xb, wkb, Kb,  4096, 2048, 2048);
  gemm_bt<3><<<gg, 256, 0, stream>>>(xb, wvb, VTb, 4096, 2048, 2048);

  rope_qk<<<32768, 256, 0, stream>>>(Qb, Kb, cosb, sinb);

  flash<<<dim3(32, 16), 512, 0, stream>>>(Qb, Kb, VTb, mask, AOb);

  gemm_bt<0><<<gg, 256, 0, stream>>>(AOb, wob, d_out, 4096, 2048, 2048);
}

// Round 13
// 304.331 us; speedup vs baseline: 40.7068x; 1.0449x over previous
//
#include <hip/hip_runtime.h>

#define B_  2
#define S_  2048
#define D_  2048
#define H_  16
#define HD_ 128

typedef float  f32x4  __attribute__((ext_vector_type(4)));
typedef __bf16 bf16x8 __attribute__((ext_vector_type(8)));
typedef __bf16 bf16x4 __attribute__((ext_vector_type(4)));

__device__ __forceinline__ void gl16(const void* g, void* l) {
  __builtin_amdgcn_global_load_lds(
      (const __attribute__((address_space(1))) unsigned int*)g,
      (__attribute__((address_space(3))) unsigned int*)l, 16, 0, 0);
}

__device__ __forceinline__ ushort f2bf(float f) {
  union { float f; unsigned u; } v; v.f = f;
  unsigned r = v.u + 0x7FFFu + ((v.u >> 16) & 1u);   // RNE
  return (ushort)(r >> 16);
}
__device__ __forceinline__ float bf2f(ushort b) {
  union { unsigned u; float f; } v; v.u = ((unsigned)b) << 16;
  return v.f;
}
__device__ __forceinline__ f32x4 fzero() {
  f32x4 v; v[0] = 0.f; v[1] = 0.f; v[2] = 0.f; v[3] = 0.f; return v;
}
// raw v_exp_f32: D = 2^S0  (HIP has no __exp2f; use the amdgcn builtin)
__device__ __forceinline__ float exp2x(float x) {
  return __builtin_amdgcn_exp2f(x);
}

// ---------------- fp32 -> bf16 convert (vectorized) ----------------
__global__ void cvt4(const float* __restrict__ s, ushort* __restrict__ d, int n4) {
  int i = blockIdx.x * blockDim.x + threadIdx.x;
  if (i >= n4) return;
  float4 v = ((const float4*)s)[i];
  ushort4 o = make_ushort4(f2bf(v.x), f2bf(v.y), f2bf(v.z), f2bf(v.w));
  ((ushort4*)d)[i] = o;
}

// ---------------- MFMA GEMM (m97 recipe, HW-verified) ----------------
// C[m,n] = sum_k A[m,k]*B[n,k], both bf16 row-major (K fast).
// 128x128 tile, BK=32, 4 waves (2x2), global_load_lds w16, dbuf LDS.
// MODE 0: fp32 row-major MxN -> (float*)
// MODE 1: bf16 scatter (B,H,S,HD) -> (ushort*)
// MODE 3: bf16 scatter (B,H,HD,S) -> (ushort*)   (transposed V)
template<int MODE>
__global__ __launch_bounds__(256, 2)
void gemm_bt(const ushort* __restrict__ A, const ushort* __restrict__ Bp,
             void* __restrict__ Cp, int M, int N, int K)
{
  __shared__ __align__(16) ushort lds[2][2][128 * 32];
  const int tid  = threadIdx.x;
  const int wave = tid >> 6, lane = tid & 63;
  const int qt = lane >> 4, ln = lane & 15;
  const int wr = wave >> 1, wc = wave & 1;
  const int bm = blockIdx.x * 128, bn = blockIdx.y * 128;

  f32x4 acc[4][4];
#pragma unroll
  for (int a = 0; a < 4; ++a)
#pragma unroll
    for (int b = 0; b < 4; ++b) acc[a][b] = fzero();

  auto stage = [&](int buf, int kt) {
#pragma unroll
    for (int it = 0; it < 2; ++it) {
      int c = it * 256 + tid;
      int row = c >> 2, ch = c & 3;
      int chs = ch ^ ((row >> 1) & 3);
      gl16(A  + (size_t)(bm + row) * K + kt + chs * 8,
           (void*)&lds[buf][0][(it * 256 + wave * 64) * 8]);
      gl16(Bp + (size_t)(bn + row) * K + kt + chs * 8,
           (void*)&lds[buf][1][(it * 256 + wave * 64) * 8]);
    }
  };

  const int nk = K >> 5;
  stage(0, 0);
  int cur = 0;
  for (int kt = 0; kt < nk; ++kt) {
    __syncthreads();                      // drains vmcnt -> buf[cur] staged
    if (kt + 1 < nk) stage(cur ^ 1, (kt + 1) << 5);
    bf16x8 af[4], bfr[4];
#pragma unroll
    for (int mf = 0; mf < 4; ++mf) {
      int row = wr * 64 + mf * 16 + ln;
      int sl = qt ^ ((row >> 1) & 3);
      af[mf] = *(const bf16x8*)&lds[cur][0][row * 32 + sl * 8];
    }
#pragma unroll
    for (int nf = 0; nf < 4; ++nf) {
      int row = wc * 64 + nf * 16 + ln;
      int sl = qt ^ ((row >> 1) & 3);
      bfr[nf] = *(const bf16x8*)&lds[cur][1][row * 32 + sl * 8];
    }
#pragma unroll
    for (int mf = 0; mf < 4; ++mf)
#pragma unroll
      for (int nf = 0; nf < 4; ++nf)
        acc[mf][nf] = __builtin_amdgcn_mfma_f32_16x16x32_bf16(
            af[mf], bfr[nf], acc[mf][nf], 0, 0, 0);
    cur ^= 1;
  }

  // epilogue: C/D layout col=lane&15, row=(lane>>4)*4+reg  [HW-verified]
#pragma unroll
  for (int mf = 0; mf < 4; ++mf)
#pragma unroll
    for (int nf = 0; nf < 4; ++nf) {
      int m0 = bm + wr * 64 + mf * 16 + qt * 4;
      int n  = bn + wc * 64 + nf * 16 + ln;
#pragma unroll
      for (int i = 0; i < 4; ++i) {
        int m = m0 + i;
        if (MODE == 0) {
          ((float*)Cp)[(size_t)m * N + n] = acc[mf][nf][i];
        } else {
          int b = m >> 11, s = m & 2047;     // m = b*S + s
          int h = n >> 7,  d = n & 127;      // n = h*HD + d
          if (MODE == 1)
            ((ushort*)Cp)[(((size_t)b * H_ + h) * S_ + s) * HD_ + d] = f2bf(acc[mf][nf][i]);
          else
            ((ushort*)Cp)[(((size_t)b * H_ + h) * HD_ + d) * S_ + s] = f2bf(acc[mf][nf][i]);
        }
      }
    }
}

// ---------------- RoPE on Q,K bf16 in (B,H,S,HD), in place ----------------
__global__ void rope_qk(ushort* __restrict__ Q, ushort* __restrict__ Kt,
                        const float* __restrict__ cs, const float* __restrict__ sn)
{
  int t = blockIdx.x * 256 + threadIdx.x;   // 2 * B*H*S * 64 threads
  int d  = t & 63;
  int rr = t >> 6;                          // 0 .. 2*B*H*S-1
  int isk = rr >> 16;                       // B*H*S = 65536
  int bhs = rr & 65535;
  int s = bhs & 2047;
  int b = bhs >> 15;
  ushort* P = isk ? Kt : Q;
  size_t ro = (size_t)bhs * HD_;
  float q0 = bf2f(P[ro + d]), q1 = bf2f(P[ro + d + 64]);
  size_t ci = ((size_t)b * S_ + s) * HD_ + d;
  float c0 = cs[ci], s0 = sn[ci], c1 = cs[ci + 64], s1 = sn[ci + 64];
  P[ro + d]      = f2bf(q0 * c0 - q1 * s0);
  P[ro + d + 64] = f2bf(q1 * c1 + q0 * s1);
}

// ---------------- flash attention: swapped QK^T, in-register softmax -------
// grid (B*H, S/128) -> head-per-XCD K/V L2 residency. 512 thr = 8 waves.
// QK^T computed as mfma(K,Q) -> S^T[k][q]: each thread owns ALL scores of
// q = ln (k = nf*16+qt*4+i). Softmax per-thread scalar mrun/lrun; row-max =
// 15 in-thread fmax + 2 shfl_xor; rescale/inv fsc fetched by 4 shfl (rare /
// epilogue-only). P written as 8B bf16x4 (granule-XOR-swizzled, 4-way max).
// K tile [64][128]: slot = ch ^ (row&7). VT tile [128][64]: slot = ch ^ (d&7).
// pt granule swizzle: write g=(nf*2+(qt>>1))^(ln&7), read g=(kk2*4+qt)^(ln&7).
// LDS 80KB -> 2 blocks/CU. exp2 domain, defer-max THR=8, dbuf K/V.
__global__ __launch_bounds__(512, 4)
void flash(const ushort* __restrict__ Q, const ushort* __restrict__ Kk,
           const ushort* __restrict__ VT, const float* __restrict__ mask,
           ushort* __restrict__ O)
{
  __shared__ __align__(16) ushort kt_s[2][64 * 128];
  __shared__ __align__(16) ushort vt_s[2][128 * 64];
  __shared__ __align__(16) ushort pt[8][16 * 64];

  const int tid = threadIdx.x;
  const int wave = tid >> 6, lane = tid & 63;
  const int qt = lane >> 4, ln = lane & 15;
  const int bh = blockIdx.x, b = bh >> 4, h = bh & 15;
  const size_t base  = (size_t)bh * S_ * HD_;
  const size_t baseT = (size_t)bh * HD_ * S_;
  const int q0 = blockIdx.y * 128 + wave * 16;
  const float L2E = 1.4426950408889634f;

  bf16x8 qf[4];
  {
    const ushort* qrow = Q + base + (size_t)(q0 + ln) * HD_;
#pragma unroll
    for (int kk = 0; kk < 4; ++kk)
      qf[kk] = *(const bf16x8*)(qrow + kk * 32 + qt * 8);
  }

  f32x4 accO[8];
#pragma unroll
  for (int i = 0; i < 8; ++i) accO[i] = fzero();
  float mrun = -1e30f;                  // per-thread: q = ln
  float lrun = 0.f;                     // per-thread partial (4 lanes share q)
  const float scale2 = 0.08838834764831845f * L2E;  // (1/sqrt(128))*log2e

  auto stageKV = [&](int buf, int k0) {
#pragma unroll
    for (int it = 0; it < 2; ++it) {         // K tile: 1024 chunks, 512 thr
      int c = it * 512 + tid;
      int row = c >> 4, ch = c & 15;
      int chs = ch ^ (row & 7);
      gl16(Kk + base + (size_t)(k0 + row) * HD_ + chs * 8,
           (void*)&kt_s[buf][(it * 512 + wave * 64) * 8]);
    }
#pragma unroll
    for (int it = 0; it < 2; ++it) {         // VT tile: 1024 chunks
      int c = it * 512 + tid;
      int row = c >> 3, ch = c & 7;
      int chs = ch ^ (row & 7);
      gl16(VT + baseT + (size_t)row * S_ + k0 + chs * 8,
           (void*)&vt_s[buf][(it * 512 + wave * 64) * 8]);
    }
  };

  stageKV(0, 0);
  int cur = 0;
  for (int k0 = 0; k0 < S_; k0 += 64) {
    __syncthreads();                         // buf[cur] staged; prev reads done
    if (k0 + 64 < S_) stageKV(cur ^ 1, k0 + 64);  // flies under compute below

    // QK^T swapped: sc[nf][i] = score(k = nf*16+qt*4+i, q = ln)
    f32x4 sc[4];
    __builtin_amdgcn_s_setprio(1);
#pragma unroll
    for (int nf = 0; nf < 4; ++nf) {
      f32x4 a = fzero();
      int row = nf * 16 + ln;
#pragma unroll
      for (int kk = 0; kk < 4; ++kk) {
        int sl = (kk * 4 + qt) ^ (row & 7);
        bf16x8 kf = *(const bf16x8*)&kt_s[cur][row * 128 + sl * 8];
        a = __builtin_amdgcn_mfma_f32_16x16x32_bf16(kf, qf[kk], a, 0, 0, 0);
      }
      sc[nf] = a;
    }
    __builtin_amdgcn_s_setprio(0);

    // scale + mask (log2 domain); k is thread-local contiguous per nf
    float sv[4][4];
#pragma unroll
    for (int nf = 0; nf < 4; ++nf) {
      float4 mk = *(const float4*)&mask[(size_t)b * S_ + k0 + nf * 16 + qt * 4];
      sv[nf][0] = sc[nf][0] * scale2 + mk.x * L2E;
      sv[nf][1] = sc[nf][1] * scale2 + mk.y * L2E;
      sv[nf][2] = sc[nf][2] * scale2 + mk.z * L2E;
      sv[nf][3] = sc[nf][3] * scale2 + mk.w * L2E;
    }

    // row max for q=ln: in-thread + 2 cross-lane hops (lanes ln,ln+16,ln+32,ln+48)
    float m = sv[0][0];
#pragma unroll
    for (int nf = 0; nf < 4; ++nf)
#pragma unroll
      for (int i = 0; i < 4; ++i) m = fmaxf(m, sv[nf][i]);
    m = fmaxf(m, __shfl_xor(m, 16));
    m = fmaxf(m, __shfl_xor(m, 32));

    // defer-max: rescale only if some q-row grew past THR=8 (exp2 domain)
    if (__any(m > mrun + 8.f)) {
      float mn = fmaxf(mrun, m);
      float fsc = exp2x(mrun - mn);
      mrun = mn;
      lrun *= fsc;
#pragma unroll
      for (int i = 0; i < 4; ++i) {
        float fq = __shfl(fsc, qt * 4 + i);  // fsc of q = qt*4+i (accO rows)
#pragma unroll
        for (int nfo = 0; nfo < 8; ++nfo) accO[nfo][i] *= fq;
      }
    }

    // P = exp2(sv - mrun), quantize bf16, 8B vector writes, per-lane sum
    float t = 0.f;
#pragma unroll
    for (int nf = 0; nf < 4; ++nf) {
      bf16x4 p4;
#pragma unroll
      for (int i = 0; i < 4; ++i) {
        float p = exp2x(sv[nf][i] - mrun);
        p4[i] = (__bf16)p;                   // HW cvt, RNE
        t += (float)p4[i];                   // sum QUANTIZED P -> exact norm
      }
      int g = (nf * 2 + (qt >> 1)) ^ (ln & 7);
      *(bf16x4*)&pt[wave][ln * 64 + g * 8 + (qt & 1) * 4] = p4;
    }
    lrun += t;

    // PV: accO[16 q][128 d] += P[16][64] * V[64][128]  (same-wave pt)
    __builtin_amdgcn_s_setprio(1);
#pragma unroll
    for (int kk2 = 0; kk2 < 2; ++kk2) {
      int gr = (kk2 * 4 + qt) ^ (ln & 7);
      bf16x8 pf = *(const bf16x8*)&pt[wave][ln * 64 + gr * 8];
#pragma unroll
      for (int nfo = 0; nfo < 8; ++nfo) {
        int vrow = nfo * 16 + ln;
        int vsl = (kk2 * 4 + qt) ^ (vrow & 7);
        bf16x8 vf = *(const bf16x8*)&vt_s[cur][vrow * 64 + vsl * 8];
        accO[nfo] = __builtin_amdgcn_mfma_f32_16x16x32_bf16(pf, vf, accO[nfo], 0, 0, 0);
      }
    }
    __builtin_amdgcn_s_setprio(0);
    cur ^= 1;
  }

  // epilogue: reduce lrun over the 4 lanes sharing q=ln, fetch inv per accO row
  lrun += __shfl_xor(lrun, 16);
  lrun += __shfl_xor(lrun, 32);
  float inv_own = 1.f / lrun;
  float inv[4];
#pragma unroll
  for (int i = 0; i < 4; ++i) inv[i] = __shfl(inv_own, qt * 4 + i);
#pragma unroll
  for (int nfo = 0; nfo < 8; ++nfo)
#pragma unroll
    for (int i = 0; i < 4; ++i) {
      size_t idx = ((size_t)b * S_ + q0 + qt * 4 + i) * D_ + h * HD_ + nfo * 16 + ln;
      O[idx] = f2bf(accO[nfo][i] * inv[i]);
    }
}

// ---------------- launcher ----------------
extern "C" void kernel_launch(void* const* d_in, const int* in_sizes, int n_in,
                              void* d_out, int out_size, void* d_ws, size_t ws_size,
                              hipStream_t stream)
{
  if (n_in != 8) return;
  if (in_sizes[0] != 8388608) return;       // x  (B,S,D)
  if (in_sizes[3] != 4096)    return;       // mask (B,S)
  if (out_size != 8388608) return;
  if (ws_size < (size_t)96 * 1024 * 1024) return;

  const float* x    = (const float*)d_in[0];
  const float* cosb = (const float*)d_in[1];
  const float* sinb = (const float*)d_in[2];
  const float* mask = (const float*)d_in[3];
  const float* wq   = (const float*)d_in[4];
  const float* wk   = (const float*)d_in[5];
  const float* wv   = (const float*)d_in[6];
  const float* wo   = (const float*)d_in[7];

  char* ws = (char*)d_ws;
  // layout (MB): xb 0..16 | wqb 16..24 | wkb 24..32 | wvb 32..40 | wob 40..48 |
  //              Qb 48..64 | Kb 64..80 | VTb 80..96
  ushort* xb  = (ushort*)(ws);
  ushort* wqb = (ushort*)(ws + 16777216);
  ushort* wkb = (ushort*)(ws + 25165824);
  ushort* wvb = (ushort*)(ws + 33554432);
  ushort* wob = (ushort*)(ws + 41943040);
  ushort* Qb  = (ushort*)(ws + 50331648);
  ushort* Kb  = (ushort*)(ws + 67108864);
  ushort* VTb = (ushort*)(ws + 83886080);
  ushort* AOb = xb;   // reuse: x_bf16 dead after QKV GEMMs

  cvt4<<<8192, 256, 0, stream>>>(x,  xb,  2097152);
  cvt4<<<4096, 256, 0, stream>>>(wq, wqb, 1048576);
  cvt4<<<4096, 256, 0, stream>>>(wk, wkb, 1048576);
  cvt4<<<4096, 256, 0, stream>>>(wv, wvb, 1048576);
  cvt4<<<4096, 256, 0, stream>>>(wo, wob, 1048576);

  dim3 gg(32, 16);   // (M/128, N/128)
  gemm_bt<1><<<gg, 256, 0, stream>>>(xb, wqb, Qb,  4096, 2048, 2048);
  gemm_bt<1><<<gg, 256, 0, stream>>>(xb, wkb, Kb,  4096, 2048, 2048);
  gemm_bt<3><<<gg, 256, 0, stream>>>(xb, wvb, VTb, 4096, 2048, 2048);

  rope_qk<<<32768, 256, 0, stream>>>(Qb, Kb, cosb, sinb);

  flash<<<dim3(32, 16), 512, 0, stream>>>(Qb, Kb, VTb, mask, AOb);

  gemm_bt<0><<<gg, 256, 0, stream>>>(AOb, wob, d_out, 4096, 2048, 2048);
}